// Round 11
// baseline (365.230 us; speedup 1.0000x reference)
//
#include <hip/hip_runtime.h>
#include <math.h>

// Problem constants
constexpr int Bc = 4, Sc = 1024, Dc = 2048, HDc = 128, Hc = 16;
constexpr int BSc = Bc * Sc;        // 4096 token rows
constexpr int KQKc = Bc * HDc;      // 512 = batch-concat K dim for SS GEMM
#define GN_EPS 1e-3f

typedef __bf16 bf16x8 __attribute__((ext_vector_type(8)));
typedef __bf16 bf16x4 __attribute__((ext_vector_type(4)));
typedef float f32x4 __attribute__((ext_vector_type(4)));

// Workspace layout (float units)
constexpr size_t OFF_Q   = 0;                                  // bf16 [H][S][512]
constexpr size_t OFF_K   = OFF_Q + (size_t)Hc * Sc * KQKc / 2; // bf16 same
constexpr size_t OFF_VB  = OFF_K + (size_t)Hc * Sc * KQKc / 2; // bf16 [BS][D]
constexpr size_t OFF_VT  = OFF_VB + (size_t)BSc * Dc / 2;      // bf16 [BH][128][1024]
constexpr size_t OFF_A   = OFF_VT + (size_t)BSc * Dc / 2;      // bf16 [H][S][S]
constexpr size_t OFF_O   = OFF_A + (size_t)Hc * Sc * Sc / 2;   // fp32 [BS][D]
constexpr size_t OFF_CT  = OFF_O + (size_t)BSc * Dc;           // [H][S]
constexpr size_t OFF_PN  = OFF_CT + (size_t)Hc * Sc;           // [H][S]
constexpr size_t OFF_XB  = OFF_PN + (size_t)Hc * Sc;           // bf16 [BS][D]
constexpr size_t OFF_WGT = OFF_XB + (size_t)BSc * Dc / 2;      // bf16 [D][D] T
constexpr size_t OFF_WOT = OFF_WGT + (size_t)Dc * Dc / 2;      // bf16 [D][D] T
constexpr size_t OFF_SUF = OFF_WOT + (size_t)Dc * Dc / 2;      // fp32 [64][9][128]
constexpr size_t OFF_T   = OFF_SUF + (size_t)64 * 9 * HDc;     // fp32 [64][8][128]
constexpr size_t OFF_WHT = OFF_T + (size_t)64 * 8 * HDc;       // bf16 [H][128][128]
constexpr size_t OFF_STAT= OFF_WHT + (size_t)Hc * HDc * HDc / 2; // fp32 [BS][2]
// KB2 / VB2 (bf16 casts of raw k, v) alias the A region (dead until k_ssm).
// G (bf16 [BS][D]) reuses the Q buffer (dead after k_ssm).
constexpr size_t OFF_KB2 = OFF_A;
constexpr size_t OFF_VB2 = OFF_A + (size_t)BSc * Dc / 2;

#define GLOAD_LDS16(gp, lp)                                               \
  __builtin_amdgcn_global_load_lds(                                       \
      (const __attribute__((address_space(1))) void*)(gp),                \
      (__attribute__((address_space(3))) void*)(lp), 16, 0, 0)

// Swizzled staging: lane l stages row l>>2 (4 lanes/row -> one 64B segment,
// coalesced) at k-chunk c = (l&3) ^ key(row), key(r) = (r>>1)&3. LDS layout:
// (r,c) at chunkbase + r*32 + (c^key(r))*8 elems. Fragment read (rl,kq) ->
// 16B unit rl*4 + (kq^key(rl)): all 64 distinct, 8-lane groups hit 8 distinct
// bank quads -> conflict-free ds_read_b128 AND coalesced global fetch.

// ---------------------------------------------------------------------------
// Shared relaxed-sync MFMA K-loop (session-verified R3/R4). Templated:
// NF = B-fragment count (4 -> N=128, 2 -> N=64 for ssm half-tiles),
// MF = A-fragment count (4 -> M=128, 2 -> M=64 for avm equal-length blocks).
// 256 threads, 4 waves (2M x 2N), per-wave (MF*16) x (NF*16), BK=64.
// LDS: A triple-buffered (staged 2 tiles ahead) + B double-buffered (1 ahead).
// Per K-tile: all ds_reads up-front, stage B(t+1) (NF loads) + A(t+2) (MF),
// 4 MFMA groups gated by compiler counted lgkmcnt; close with lgkmcnt(0) +
// counted vmcnt(MF) (A's MF loads are always the newest; B's NF retire) +
// ONE s_barrier. Requires ntk >= 2.
constexpr int ABUFE = 128 * 64;       // elems per A buffer at MF=4 (16 KB)
constexpr int BBUFE = 128 * 64;       // elems per B buffer at NF=4 (16 KB)
constexpr int MG_LDS = (3 * ABUFE + 2 * BBUFE) * 2;  // 81920 B
constexpr int PJ_LDS = 4 * 8192 * 2;                 // 65536 B (k_projm)
constexpr int AV_LDS = (3 * 64 * 64 + 2 * BBUFE) * 2;  // 57344 B (k_avm MF=2)

template <int ASTR, int BSTR, int NF = 4, int MF = 4>
__device__ __forceinline__ void mfma_loop128(const __bf16* __restrict__ Abase,
                                             const __bf16* __restrict__ Bbase,
                                             const int ntk,
                                             __bf16* As, __bf16* Bs,
                                             const int wave, const int lane,
                                             f32x4 acc[MF][NF]) {
  constexpr int NH = NF / 2;                        // n per group
  constexpr int MH = MF / 2;                        // m per group
  constexpr int ABE = MF * 2048;                    // elems per A buffer
  const int wr = wave >> 1, wc = wave & 1;          // 2(M) x 2(N) waves
  const int lr = lane >> 2;                         // staging row in chunk
  const int lkx = ((lane & 3) ^ ((lane >> 3) & 3)) * 8;  // staging k offset
  const int rl = lane & 15, kq = lane >> 4;         // frag row / k-quarter
  const int swo = rl * 32 + ((kq ^ ((rl >> 1) & 3)) * 8);

#define VMW_MF()                                                            \
  do {                                                                      \
    if constexpr (MF == 4)                                                  \
      asm volatile("s_waitcnt vmcnt(4)" ::: "memory");                      \
    else                                                                    \
      asm volatile("s_waitcnt vmcnt(2)" ::: "memory");                      \
  } while (0)

  // stage: one 16-row x 32-k chunk per wave per call; ci = i*4 + wave.
#define SA_(i, kt, bsel) do {                                               \
    const int ci_ = (i) * 4 + wave;                                         \
    GLOAD_LDS16(Abase + (size_t)((ci_ >> 1) * 16 + lr) * ASTR               \
                    + (kt) * 64 + (ci_ & 1) * 32 + lkx,                     \
                As + (bsel) * ABE + ci_ * 512);                             \
  } while (0)
#define SB_(j, kt, bsel) do {                                               \
    const int ci_ = (j) * 4 + wave;                                         \
    GLOAD_LDS16(Bbase + (size_t)((ci_ >> 1) * 16 + lr) * BSTR               \
                    + (kt) * 64 + (ci_ & 1) * 32 + lkx,                     \
                Bs + (bsel) * BBUFE + ci_ * 512);                           \
  } while (0)

  // Prologue: A(0), B(0), A(1)  (B(1) staged inside tile 0).
  #pragma unroll
  for (int i = 0; i < MF; ++i) SA_(i, 0, 0);
  #pragma unroll
  for (int j = 0; j < NF; ++j) SB_(j, 0, 0);
  #pragma unroll
  for (int i = 0; i < MF; ++i) SA_(i, 1, 1);
  __builtin_amdgcn_sched_barrier(0);
  VMW_MF();                                         // A(0)+B(0) landed
  __builtin_amdgcn_sched_barrier(0);
  __builtin_amdgcn_s_barrier();

  int cbA = 0;                         // A buffer holding tile t
  for (int t = 0; t < ntk; ++t) {
    const int sbA = (cbA + 2 >= 3) ? cbA - 1 : cbA + 2;  // (cbA+2)%3
    const __bf16* Ac = As + cbA * ABE;
    const __bf16* Bc = Bs + (t & 1) * BBUFE;
    bf16x8 a[MF][2], b[NF][2];
    // --- issue all ds_reads, order a-lo, b-lo, a-hi, b-hi ---
    #pragma unroll
    for (int m = 0; m < MH; ++m)
      #pragma unroll
      for (int kc = 0; kc < 2; ++kc)
        a[m][kc] = *(const bf16x8*)&Ac[((wr * MF + m) * 2 + kc) * 512 + swo];
    #pragma unroll
    for (int n = 0; n < NH; ++n)
      #pragma unroll
      for (int kc = 0; kc < 2; ++kc)
        b[n][kc] = *(const bf16x8*)&Bc[((wc * NF + n) * 2 + kc) * 512 + swo];
    #pragma unroll
    for (int m = MH; m < MF; ++m)
      #pragma unroll
      for (int kc = 0; kc < 2; ++kc)
        a[m][kc] = *(const bf16x8*)&Ac[((wr * MF + m) * 2 + kc) * 512 + swo];
    #pragma unroll
    for (int n = NH; n < NF; ++n)
      #pragma unroll
      for (int kc = 0; kc < 2; ++kc)
        b[n][kc] = *(const bf16x8*)&Bc[((wc * NF + n) * 2 + kc) * 512 + swo];
    // --- issue staging: B for t+1, A for t+2 (order matters for vmcnt) ---
    if (t + 1 < ntk) {
      #pragma unroll
      for (int j = 0; j < NF; ++j) SB_(j, t + 1, (t + 1) & 1);
    }
    if (t + 2 < ntk) {
      #pragma unroll
      for (int i = 0; i < MF; ++i) SA_(i, t + 2, sbA);
    }
    __builtin_amdgcn_sched_barrier(0);
    // --- G1: m-lo x n-lo (compiler counted lgkmcnt gates) ---
    __builtin_amdgcn_s_setprio(1);
    #pragma unroll
    for (int kc = 0; kc < 2; ++kc)
      #pragma unroll
      for (int m = 0; m < MH; ++m)
        #pragma unroll
        for (int n = 0; n < NH; ++n)
          acc[m][n] = __builtin_amdgcn_mfma_f32_16x16x32_bf16(
              a[m][kc], b[n][kc], acc[m][n], 0, 0, 0);
    __builtin_amdgcn_s_setprio(0);
    __builtin_amdgcn_sched_barrier(0);
    // --- G2: m-hi x n-lo ---
    __builtin_amdgcn_s_setprio(1);
    #pragma unroll
    for (int kc = 0; kc < 2; ++kc)
      #pragma unroll
      for (int m = MH; m < MF; ++m)
        #pragma unroll
        for (int n = 0; n < NH; ++n)
          acc[m][n] = __builtin_amdgcn_mfma_f32_16x16x32_bf16(
              a[m][kc], b[n][kc], acc[m][n], 0, 0, 0);
    __builtin_amdgcn_s_setprio(0);
    __builtin_amdgcn_sched_barrier(0);
    // --- G3: m-lo x n-hi ---
    __builtin_amdgcn_s_setprio(1);
    #pragma unroll
    for (int kc = 0; kc < 2; ++kc)
      #pragma unroll
      for (int m = 0; m < MH; ++m)
        #pragma unroll
        for (int n = NH; n < NF; ++n)
          acc[m][n] = __builtin_amdgcn_mfma_f32_16x16x32_bf16(
              a[m][kc], b[n][kc], acc[m][n], 0, 0, 0);
    __builtin_amdgcn_s_setprio(0);
    __builtin_amdgcn_sched_barrier(0);
    // --- G4: m-hi x n-hi ---
    __builtin_amdgcn_s_setprio(1);
    #pragma unroll
    for (int kc = 0; kc < 2; ++kc)
      #pragma unroll
      for (int m = MH; m < MF; ++m)
        #pragma unroll
        for (int n = NH; n < NF; ++n)
          acc[m][n] = __builtin_amdgcn_mfma_f32_16x16x32_bf16(
              a[m][kc], b[n][kc], acc[m][n], 0, 0, 0);
    __builtin_amdgcn_s_setprio(0);
    __builtin_amdgcn_sched_barrier(0);
    // --- tile close: drain my reads (free by now), prove t+1 staged, bar ---
    asm volatile("s_waitcnt lgkmcnt(0)" ::: "memory");
    __builtin_amdgcn_sched_barrier(0);
    if (t + 2 < ntk) {                 // newest MF = SA(t+2); SB(t+1) retired
      VMW_MF();
    } else if (t + 1 < ntk) {          // tail: drain SB(t+1)
      asm volatile("s_waitcnt vmcnt(0)" ::: "memory");
    }
    __builtin_amdgcn_sched_barrier(0);
    __builtin_amdgcn_s_barrier();
    cbA = (cbA + 1 >= 3) ? 0 : cbA + 1;
  }
#undef SA_
#undef SB_
#undef VMW_MF
}

// ---------------------------------------------------------------------------
// Decay tables + zero the TP / STAT accumulators (inside the graph, so each
// replay re-zeroes before k_vt / k_avm atomics).
__global__ __launch_bounds__(256) void k_tables(float* __restrict__ ct,
                                                float* __restrict__ pn,
                                                float* __restrict__ TP,
                                                float* __restrict__ STAT) {
  int idx = blockIdx.x * 256 + threadIdx.x;   // 0 .. H*S-1 (16384)
  int h = idx >> 10, t = idx & 1023;
  double gamma = 1.0 - exp2(-(double)(5 + h));
  double l2g = log2(gamma);
  double r = 1.0 / gamma;
  double rowsum = (exp2(-(double)(t + 1) * l2g) - 1.0) / (r - 1.0);
  ct[idx] = (float)(exp2((double)t * l2g) / sqrt(rowsum));
  pn[idx] = (float)exp2(-(double)t * l2g);
  float4 z4 = {0.f, 0.f, 0.f, 0.f};
  *(float4*)(TP + (size_t)idx * 4) = z4;      // 16384*4 = 65536 floats
  if (idx < BSc * 2) STAT[idx] = 0.f;         // 8192 floats
}

// ---------------------------------------------------------------------------
// fp32 -> bf16 cast, 8 elems/thread; grid.y selects which tensor (fused 3x).
__global__ __launch_bounds__(256) void k_cast83(const float* __restrict__ s0,
                                                const float* __restrict__ s1,
                                                const float* __restrict__ s2,
                                                __bf16* __restrict__ d0,
                                                __bf16* __restrict__ d1,
                                                __bf16* __restrict__ d2) {
  const int y = blockIdx.y;
  const float* src = (y == 0) ? s0 : (y == 1) ? s1 : s2;
  __bf16* dst = (y == 0) ? d0 : (y == 1) ? d1 : d2;
  size_t i = ((size_t)blockIdx.x * 256 + threadIdx.x) * 8;
  float4 a = *(const float4*)(src + i);
  float4 b = *(const float4*)(src + i + 4);
  bf16x8 o;
  o[0] = (__bf16)a.x; o[1] = (__bf16)a.y; o[2] = (__bf16)a.z; o[3] = (__bf16)a.w;
  o[4] = (__bf16)b.x; o[5] = (__bf16)b.y; o[6] = (__bf16)b.z; o[7] = (__bf16)b.w;
  *(bf16x8*)(dst + i) = o;
}

// ---------------------------------------------------------------------------
// Transpose-cast x2: dst[n][k] = (bf16) src[k][n], 2048x2048; z selects wg/wo.
__global__ __launch_bounds__(256) void k_castT2(const float* __restrict__ s0,
                                                const float* __restrict__ s1,
                                                __bf16* __restrict__ d0,
                                                __bf16* __restrict__ d1) {
  __shared__ float t[32][33];
  const int bx = blockIdx.x, by = blockIdx.y;
  const float* src = blockIdx.z ? s1 : s0;
  __bf16* dst = blockIdx.z ? d1 : d0;
  const int tid = threadIdx.x;
  const int lx = tid & 31, ly = tid >> 5;   // 32 x 8
  #pragma unroll
  for (int r = 0; r < 32; r += 8)
    t[ly + r][lx] = src[(size_t)(by * 32 + ly + r) * Dc + bx * 32 + lx];
  __syncthreads();
  #pragma unroll
  for (int r = 0; r < 32; r += 8)
    dst[(size_t)(bx * 32 + ly + r) * Dc + by * 32 + lx] = (__bf16)t[lx][ly + r];
}

// ---------------------------------------------------------------------------
// Per-head transpose-cast of Wh: WhT[h][e][d] = (bf16) Wh[h][d][e].
__global__ __launch_bounds__(256) void k_whT(const float* __restrict__ Wh,
                                             __bf16* __restrict__ WhT) {
  __shared__ float t[32][33];
  const int h = blockIdx.z;
  const int d0 = blockIdx.x * 32, e0 = blockIdx.y * 32;
  const int tid = threadIdx.x;
  const int lx = tid & 31, ly = tid >> 5;
  #pragma unroll
  for (int r = 0; r < 32; r += 8)
    t[ly + r][lx] = Wh[(size_t)h * HDc * HDc + (d0 + ly + r) * HDc + e0 + lx];
  __syncthreads();
  #pragma unroll
  for (int r = 0; r < 32; r += 8)
    WhT[(size_t)h * HDc * HDc + (e0 + ly + r) * HDc + d0 + lx] =
        (__bf16)t[lx][ly + r];
}

// ---------------------------------------------------------------------------
// MFMA projections, SINGLE-STAGE (K=128 fits in LDS). Stage X-panel (32 KB) +
// W-panel (32 KB) once, one vmcnt(0) + one barrier, 128 MFMA/wave straight
// through. 64 KiB LDS -> 2 WGs/CU; 1536 blocks stream 6 rounds/CU.
// z=0: Xb -> Q layout [h][s][b*HD]; z=1: Kb2 -> K layout; z=2: Vb2 -> Vp.
__global__ __launch_bounds__(256, 2) void k_projm(const __bf16* __restrict__ Xb,
                                                  const __bf16* __restrict__ Kb2,
                                                  const __bf16* __restrict__ Vb2,
                                                  const __bf16* __restrict__ WhT,
                                                  __bf16* __restrict__ Qo,
                                                  __bf16* __restrict__ Ko,
                                                  __bf16* __restrict__ Vo) {
  extern __shared__ __bf16 lds[];
  __bf16* Xs = lds;                    // 2 x 8192 (kt-major)
  __bf16* Ws = lds + 2 * 8192;         // 2 x 8192
  const int r0 = blockIdx.x * 128;
  const int h = blockIdx.y;
  const int z = blockIdx.z;
  const __bf16* src = (z == 0) ? Xb : (z == 1) ? Kb2 : Vb2;
  const __bf16* wsrc = WhT + (size_t)h * HDc * HDc;
  const int tid = threadIdx.x;
  const int wave = tid >> 6, lane = tid & 63;
  const int wr = wave >> 1, wc = wave & 1;
  const int lr = lane >> 2;
  const int lkx = ((lane & 3) ^ ((lane >> 3) & 3)) * 8;
  const int rl = lane & 15, kq = lane >> 4;
  const int swo = rl * 32 + ((kq ^ ((rl >> 1) & 3)) * 8);
  // stage both K-halves of both operands (same chunk swizzle as the loop)
  #pragma unroll
  for (int kt = 0; kt < 2; ++kt) {
    #pragma unroll
    for (int i = 0; i < 4; ++i) {
      const int ci = i * 4 + wave;
      const int row = (ci >> 1) * 16 + lr;
      const int ko = kt * 64 + (ci & 1) * 32 + lkx;
      GLOAD_LDS16(src + (size_t)(r0 + row) * Dc + h * HDc + ko,
                  Xs + kt * 8192 + ci * 512);
      GLOAD_LDS16(wsrc + (size_t)row * HDc + ko, Ws + kt * 8192 + ci * 512);
    }
  }
  __builtin_amdgcn_sched_barrier(0);
  asm volatile("s_waitcnt vmcnt(0)" ::: "memory");
  __builtin_amdgcn_sched_barrier(0);
  __builtin_amdgcn_s_barrier();
  f32x4 acc[4][4] = {{}};
  #pragma unroll
  for (int kt = 0; kt < 2; ++kt) {
    bf16x8 a[4][2], b[4][2];
    #pragma unroll
    for (int m = 0; m < 4; ++m)
      #pragma unroll
      for (int kc = 0; kc < 2; ++kc)
        a[m][kc] =
            *(const bf16x8*)&Xs[kt * 8192 + ((wr * 4 + m) * 2 + kc) * 512 + swo];
    #pragma unroll
    for (int n = 0; n < 4; ++n)
      #pragma unroll
      for (int kc = 0; kc < 2; ++kc)
        b[n][kc] =
            *(const bf16x8*)&Ws[kt * 8192 + ((wc * 4 + n) * 2 + kc) * 512 + swo];
    #pragma unroll
    for (int kc = 0; kc < 2; ++kc)
      #pragma unroll
      for (int m = 0; m < 4; ++m)
        #pragma unroll
        for (int n = 0; n < 4; ++n)
          acc[m][n] = __builtin_amdgcn_mfma_f32_16x16x32_bf16(
              a[m][kc], b[n][kc], acc[m][n], 0, 0, 0);
  }
  #pragma unroll
  for (int mi = 0; mi < 4; ++mi) {
    #pragma unroll
    for (int nj = 0; nj < 4; ++nj) {
      const int col = wc * 64 + nj * 16 + rl;
      #pragma unroll
      for (int r = 0; r < 4; ++r) {
        const int row = r0 + wr * 64 + mi * 16 + kq * 4 + r;
        const __bf16 v = (__bf16)acc[mi][nj][r];
        if (z == 2) {
          Vo[(size_t)row * Dc + h * HDc + col] = v;
        } else {
          const int s = row & 1023, bb = row >> 10;
          __bf16* dst = (z == 0) ? Qo : Ko;
          dst[((size_t)(h * Sc + s) * Bc + bb) * HDc + col] = v;
        }
      }
    }
  }
}

// ---------------------------------------------------------------------------
// Transpose-cast V + fused per-128-t-tile column sums (replaces k_vsum):
// Vt[(b*16+h)][e][t] = VB[b][t][h*128+e]; TP[bh][t0/128][e] += sum_t V.
__global__ __launch_bounds__(256) void k_vt(const __bf16* __restrict__ VB,
                                            __bf16* __restrict__ Vt,
                                            float* __restrict__ TP) {
  __shared__ float tl[32][33];
  __shared__ float rs[8][32];
  const int bh = blockIdx.z, bb = bh >> 4, h = bh & 15;
  const int t0 = blockIdx.x * 32, e0 = blockIdx.y * 32;
  const int tid = threadIdx.x;
  const int lx = tid & 31, ly = tid >> 5;
  float ps = 0.f;
  #pragma unroll
  for (int r = 0; r < 32; r += 8) {
    const float v =
        (float)VB[(size_t)(bb * Sc + t0 + ly + r) * Dc + h * HDc + e0 + lx];
    tl[ly + r][lx] = v;
    ps += v;
  }
  rs[ly][lx] = ps;
  __syncthreads();
  #pragma unroll
  for (int r = 0; r < 32; r += 8)
    Vt[((size_t)bh * HDc + e0 + ly + r) * Sc + t0 + lx] = (__bf16)tl[lx][ly + r];
  if (ly == 0) {
    float s = ((rs[0][lx] + rs[1][lx]) + (rs[2][lx] + rs[3][lx])) +
              ((rs[4][lx] + rs[5][lx]) + (rs[6][lx] + rs[7][lx]));
    atomicAdd(&TP[((size_t)bh * 8 + (t0 >> 7)) * HDc + e0 + lx], s);
  }
}

// ---------------------------------------------------------------------------
// Stage 2: suffix-scan tiles -> SufV[bh][j][e] = sum_{t >= 128*j} V[b,t,h,e].
__global__ __launch_bounds__(128) void k_vscan(const float* __restrict__ T,
                                               float* __restrict__ SufV) {
  const int bh = blockIdx.x;
  const int e = threadIdx.x;
  float acc = 0.f;
  SufV[((size_t)bh * 9 + 8) * HDc + e] = 0.f;
  for (int jj = 7; jj >= 1; --jj) {
    acc += T[((size_t)bh * 8 + jj) * HDc + e];
    SufV[((size_t)bh * 9 + jj) * HDc + e] = acc;
  }
}

// ---------------------------------------------------------------------------
// SS via shared loop (NF=2 half-tiles): A[h][s][t] =
// clamp(|ct[t]*pn[s]*(Q·K^T)/sqrt(128)|,1) for t<=s, 1.0 for t>s in-tile.
// Grid (8,9,16) = 1152 blocks, ONE 128(s)x64(t) half-tile each -> all 256 CUs
// active (R7/R9 grid idled 112 CUs; measured 9% occ). id mod 8 == bx keeps
// XCD K-panel-column specialization.
//   by<8, bx<=by -> tile (r=by, c=bx) half 0
//   by<8, bx> by -> tile (r=bx, c=by) half 1   (mirror pairing)
//   by==8        -> diagonal tile (bx,bx) half 1
__global__ __launch_bounds__(256, 2) void k_ssm(const __bf16* __restrict__ Q,
                                                const __bf16* __restrict__ Kb,
                                                const float* __restrict__ ct,
                                                const float* __restrict__ pn,
                                                __bf16* __restrict__ A) {
  const int bx = blockIdx.x, by = blockIdx.y;
  int r, c, half;
  if (by == 8)       { r = bx; c = bx; half = 1; }
  else if (bx > by)  { r = bx; c = by; half = 1; }
  else               { r = by; c = bx; half = 0; }
  extern __shared__ __bf16 lds[];
  __bf16* As = lds;
  __bf16* Bs = lds + 3 * ABUFE;
  const int h = blockIdx.z;
  const int s0 = r * 128;
  const int t0 = c * 128 + half * 64;
  const int tid = threadIdx.x;
  __bf16* Ah = A + (size_t)h * Sc * Sc;
  const int wave = tid >> 6, lane = tid & 63;
  f32x4 acc[4][2] = {{}};
  mfma_loop128<KQKc, KQKc, 2>(Q + (size_t)(h * Sc + s0) * KQKc,
                              Kb + (size_t)(h * Sc + t0) * KQKc, KQKc / 64,
                              As, Bs, wave, lane, acc);
  const int wr = wave >> 1, wc = wave & 1;
  const int rl = lane & 15, kq = lane >> 4;
  const float rs = 0.088388347648318447f;  // 1/sqrt(128)
  #pragma unroll
  for (int mi = 0; mi < 4; ++mi) {
    #pragma unroll
    for (int nj = 0; nj < 2; ++nj) {
      const int t = t0 + wc * 32 + nj * 16 + rl;
      const float ctv = ct[h * Sc + t] * rs;
      #pragma unroll
      for (int rr = 0; rr < 4; ++rr) {
        const int s = s0 + wr * 64 + mi * 16 + kq * 4 + rr;
        float v = 1.0f;
        if (t <= s) v = fmaxf(fabsf(ctv * pn[h * Sc + s] * acc[mi][nj][rr]), 1.0f);
        Ah[(size_t)s * Sc + t] = (__bf16)v;
      }
    }
  }
}

// ---------------------------------------------------------------------------
// O = A @ V via shared loop, MF=2 (64-row s-tiles), EQUAL-LENGTH blocks.
// R10's pairing (2,16),(4,14),(6,12),(8,10) had equal SUMS but mismatched
// concurrent lengths: the short WG finished early, the long one ran solo
// (overlap fraction ~0.43; measured 11.8% occ, 7.6% MfmaUtil). Now each
// block = (itile j, s-half hh) then (itile 7-j, s-half 1-hh), sequentially:
// exactly 18 K-tiles for ALL 512 blocks -> both co-resident WGs overlap for
// their entire lifetime. Coverage: itile q<4 by blocks (j=q, hh=0/1) seg0;
// q>=4 by (j=7-q, hh) seg1 -> each (itile, half) written exactly once.
// All-ones region added as fp32 SufV. Epilogue accumulates GroupNorm stats
// into STAT via 16-lane shfl reduce + 2 atomics per row per wave.
__global__ __launch_bounds__(256, 2) void k_avm(const __bf16* __restrict__ A,
                                                const __bf16* __restrict__ Vt,
                                                const float* __restrict__ SufV,
                                                float* __restrict__ O,
                                                float* __restrict__ STAT) {
  extern __shared__ __bf16 lds[];
  __bf16* As = lds;                    // 3 x 4096 (MF=2)
  __bf16* Bs = lds + 3 * 64 * 64;      // 2 x 8192
  const int bh = blockIdx.z, bb = bh >> 4, h = bh & 15;
  const int j = (int)blockIdx.x >> 1;          // 0..3
  const int hh0 = (int)blockIdx.x & 1;
  const int tid = threadIdx.x;
  const int wave = tid >> 6, lane = tid & 63;
  const int wr = wave >> 1, wc = wave & 1;
  const int rl = lane & 15, kq = lane >> 4;
  #pragma unroll
  for (int seg = 0; seg < 2; ++seg) {
    const int itile = seg ? 7 - j : j;
    const int hh = seg ? 1 - hh0 : hh0;
    const int s0 = itile * 128 + hh * 64;
    f32x4 acc[2][4] = {{}};
    mfma_loop128<Sc, Sc, 4, 2>(A + (size_t)(h * Sc + s0) * Sc,
                               Vt + (size_t)bh * HDc * Sc, (itile + 1) * 2,
                               As, Bs, wave, lane, acc);
    const float* sufr = SufV + ((size_t)bh * 9 + (itile + 1)) * HDc;
    #pragma unroll
    for (int mi = 0; mi < 2; ++mi) {
      #pragma unroll
      for (int r = 0; r < 4; ++r) {
        const int s = s0 + wr * 32 + mi * 16 + kq * 4 + r;
        const size_t orow = (size_t)(bb * Sc + s);
        float vs = 0.f, vq = 0.f;
        #pragma unroll
        for (int nj = 0; nj < 4; ++nj) {
          const int e = wc * 64 + nj * 16 + rl;
          const float v = acc[mi][nj][r] + sufr[e];
          O[orow * Dc + h * HDc + e] = v;
          vs += v;
          vq += v * v;
        }
        #pragma unroll
        for (int m = 1; m < 16; m <<= 1) {
          vs += __shfl_xor(vs, m);
          vq += __shfl_xor(vq, m);
        }
        if (rl == 0) {
          atomicAdd(&STAT[orow * 2], vs);
          atomicAdd(&STAT[orow * 2 + 1], vq);
        }
      }
    }
  }
}

// ---------------------------------------------------------------------------
// bf16 MFMA GEMM via shared loop: C = A @ Bt^T. M=4096, N=2048, K=2048
// (NTK=32). Grid 16(N) x 32(M) = 512 WGs = 2/CU. XCD-chunked swizzle.
// mode 0: Gout = bf16(relu(acc) * groupnorm(Y; STAT, gw, bw))  (gnorm fused:
//         mu/var from STAT one-pass).
// mode 1: Fout = acc (fp32).
__global__ __launch_bounds__(256, 2) void k_mgemm(const __bf16* __restrict__ Ab,
                                                  const __bf16* __restrict__ Bt,
                                                  const float* __restrict__ Y,
                                                  const float* __restrict__ gw,
                                                  const float* __restrict__ bw,
                                                  const float* __restrict__ STAT,
                                                  __bf16* __restrict__ Gout,
                                                  float* __restrict__ Fout,
                                                  int mode) {
  extern __shared__ __bf16 lds[];
  __bf16* As = lds;
  __bf16* Bs = lds + 3 * ABUFE;
  // XCD-chunked swizzle: 512 WGs, 64 consecutive work-ids per XCD ->
  // each XCD owns 4 adjacent A-panels (4 x 0.5MB) x full B sweep.
  int wid = blockIdx.y * gridDim.x + blockIdx.x;
  wid = (wid & 7) * 64 + (wid >> 3);
  const int r0 = (wid >> 4) * 128;    // M block (32)
  const int c0 = (wid & 15) * 128;    // N block (16)
  const int tid = threadIdx.x;
  const int wave = tid >> 6, lane = tid & 63;
  f32x4 acc[4][4] = {{}};
  mfma_loop128<Dc, Dc>(Ab + (size_t)r0 * Dc, Bt + (size_t)c0 * Dc, Dc / 64,
                       As, Bs, wave, lane, acc);
  const int wr = wave >> 1, wc = wave & 1;
  const int rl = lane & 15, kq = lane >> 4;
  if (mode == 0) {
    #pragma unroll
    for (int mi = 0; mi < 4; ++mi) {
      #pragma unroll
      for (int r = 0; r < 4; ++r) {
        const int row = r0 + wr * 64 + mi * 16 + kq * 4 + r;
        const float mu = STAT[(size_t)row * 2] * (1.0f / Dc);
        const float va = STAT[(size_t)row * 2 + 1] * (1.0f / Dc) - mu * mu;
        const float inv = rsqrtf(va + GN_EPS);
        #pragma unroll
        for (int nj = 0; nj < 4; ++nj) {
          const int col = c0 + wc * 64 + nj * 16 + rl;
          const size_t idx = (size_t)row * Dc + col;
          const float yv = (Y[idx] - mu) * inv * gw[col] + bw[col];
          Gout[idx] = (__bf16)(fmaxf(acc[mi][nj][r], 0.f) * yv);
        }
      }
    }
  } else {
    #pragma unroll
    for (int mi = 0; mi < 4; ++mi) {
      #pragma unroll
      for (int nj = 0; nj < 4; ++nj) {
        const int col = c0 + wc * 64 + nj * 16 + rl;
        #pragma unroll
        for (int r = 0; r < 4; ++r) {
          const int row = r0 + wr * 64 + mi * 16 + kq * 4 + r;
          Fout[(size_t)row * Dc + col] = acc[mi][nj][r];
        }
      }
    }
  }
}

// ---------------------------------------------------------------------------
extern "C" void kernel_launch(void* const* d_in, const int* in_sizes, int n_in,
                              void* d_out, int out_size, void* d_ws, size_t ws_size,
                              hipStream_t stream) {
  const float* x  = (const float*)d_in[0];
  const float* k  = (const float*)d_in[1];
  const float* v  = (const float*)d_in[2];
  const float* Wh = (const float*)d_in[3];
  const float* wg = (const float*)d_in[4];
  const float* wo = (const float*)d_in[5];
  const float* gg = (const float*)d_in[6];
  const float* gb = (const float*)d_in[7];
  float* ws = (float*)d_ws;
  __bf16* Q   = (__bf16*)(ws + OFF_Q);
  __bf16* Kp  = (__bf16*)(ws + OFF_K);
  __bf16* VB  = (__bf16*)(ws + OFF_VB);
  __bf16* Vt  = (__bf16*)(ws + OFF_VT);
  __bf16* A   = (__bf16*)(ws + OFF_A);
  float*  O   = ws + OFF_O;
  float*  CT  = ws + OFF_CT;
  float*  PN  = ws + OFF_PN;
  __bf16* XB  = (__bf16*)(ws + OFF_XB);
  __bf16* WGT = (__bf16*)(ws + OFF_WGT);
  __bf16* WOT = (__bf16*)(ws + OFF_WOT);
  float*  SUF = ws + OFF_SUF;
  float*  TP  = ws + OFF_T;
  __bf16* WHT = (__bf16*)(ws + OFF_WHT);
  float*  STAT= ws + OFF_STAT;
  __bf16* KB2 = (__bf16*)(ws + OFF_KB2);  // aliases A (dead until k_ssm)
  __bf16* VB2 = (__bf16*)(ws + OFF_VB2);  // aliases A second half
  __bf16* G   = (__bf16*)(ws + OFF_Q);    // reuse Q region (dead after k_ssm)

  // one-time opt-in for dynamic LDS (host-side, graph-capture safe)
  static bool attr_done = false;
  if (!attr_done) {
    (void)hipFuncSetAttribute((const void*)k_mgemm,
                              hipFuncAttributeMaxDynamicSharedMemorySize,
                              MG_LDS);
    (void)hipFuncSetAttribute((const void*)k_projm,
                              hipFuncAttributeMaxDynamicSharedMemorySize,
                              PJ_LDS);
    (void)hipFuncSetAttribute((const void*)k_ssm,
                              hipFuncAttributeMaxDynamicSharedMemorySize,
                              MG_LDS);
    (void)hipFuncSetAttribute((const void*)k_avm,
                              hipFuncAttributeMaxDynamicSharedMemorySize,
                              AV_LDS);
    attr_done = true;
  }

  k_tables<<<Hc * Sc / 256, 256, 0, stream>>>(CT, PN, TP, STAT);
  k_cast83<<<dim3((BSc * Dc) / (256 * 8), 3), 256, 0, stream>>>(
      x, k, v, XB, KB2, VB2);
  k_castT2<<<dim3(Dc / 32, Dc / 32, 2), 256, 0, stream>>>(wg, wo, WGT, WOT);
  k_whT<<<dim3(4, 4, Hc), 256, 0, stream>>>(Wh, WHT);
  k_projm<<<dim3(BSc / 128, Hc, 3), 256, PJ_LDS, stream>>>(XB, KB2, VB2, WHT,
                                                           Q, Kp, VB);
  k_vt<<<dim3(Sc / 32, HDc / 32, Bc * Hc), 256, 0, stream>>>(VB, Vt, TP);
  k_vscan<<<Bc * Hc, 128, 0, stream>>>(TP, SUF);
  k_ssm<<<dim3(8, 9, Hc), 256, MG_LDS, stream>>>(Q, Kp, CT, PN, A);
  k_avm<<<dim3(8, 1, Bc * Hc), 256, AV_LDS, stream>>>(A, Vt, SUF, O, STAT);
  k_mgemm<<<dim3(16, 32), 256, MG_LDS, stream>>>(XB, WGT, O, gg, gb, STAT, G,
                                                 nullptr, 0);
  k_mgemm<<<dim3(16, 32), 256, MG_LDS, stream>>>(G, WOT, nullptr, nullptr,
                                                 nullptr, nullptr, nullptr,
                                                 (float*)d_out, 1);
}

// Round 12
// 346.104 us; speedup vs baseline: 1.0553x; 1.0553x over previous
//
#include <hip/hip_runtime.h>
#include <math.h>

// Problem constants
constexpr int Bc = 4, Sc = 1024, Dc = 2048, HDc = 128, Hc = 16;
constexpr int BSc = Bc * Sc;        // 4096 token rows
constexpr int KQKc = Bc * HDc;      // 512 = batch-concat K dim for SS GEMM
#define GN_EPS 1e-3f

typedef __bf16 bf16x8 __attribute__((ext_vector_type(8)));
typedef __bf16 bf16x4 __attribute__((ext_vector_type(4)));
typedef float f32x4 __attribute__((ext_vector_type(4)));

// Workspace layout (float units)
constexpr size_t OFF_Q   = 0;                                  // bf16 [H][S][512]
constexpr size_t OFF_K   = OFF_Q + (size_t)Hc * Sc * KQKc / 2; // bf16 same
constexpr size_t OFF_VB  = OFF_K + (size_t)Hc * Sc * KQKc / 2; // bf16 [BS][D] (dead; kept for layout)
constexpr size_t OFF_VT  = OFF_VB + (size_t)BSc * Dc / 2;      // bf16 [BH][128][1024]
constexpr size_t OFF_A   = OFF_VT + (size_t)BSc * Dc / 2;      // bf16 [H][S][S]
constexpr size_t OFF_O   = OFF_A + (size_t)Hc * Sc * Sc / 2;   // fp32 [BS][D]
constexpr size_t OFF_CT  = OFF_O + (size_t)BSc * Dc;           // [H][S]
constexpr size_t OFF_PN  = OFF_CT + (size_t)Hc * Sc;           // [H][S]
constexpr size_t OFF_XB  = OFF_PN + (size_t)Hc * Sc;           // bf16 [BS][D]
constexpr size_t OFF_WGT = OFF_XB + (size_t)BSc * Dc / 2;      // bf16 [D][D] T
constexpr size_t OFF_WOT = OFF_WGT + (size_t)Dc * Dc / 2;      // bf16 [D][D] T
constexpr size_t OFF_SUF = OFF_WOT + (size_t)Dc * Dc / 2;      // fp32 [64][9][128]
constexpr size_t OFF_T   = OFF_SUF + (size_t)64 * 9 * HDc;     // fp32 [64][8][128]
constexpr size_t OFF_WHT = OFF_T + (size_t)64 * 8 * HDc;       // bf16 [H][128][128]
constexpr size_t OFF_STAT= OFF_WHT + (size_t)Hc * HDc * HDc / 2; // fp32 [BS][2]
// KB2 / VB2 (bf16 casts of raw k, v) alias the A region (dead until k_ssm).
// G (bf16 [BS][D]) reuses the Q buffer (dead after k_ssm).
constexpr size_t OFF_KB2 = OFF_A;
constexpr size_t OFF_VB2 = OFF_A + (size_t)BSc * Dc / 2;

#define GLOAD_LDS16(gp, lp)                                               \
  __builtin_amdgcn_global_load_lds(                                       \
      (const __attribute__((address_space(1))) void*)(gp),                \
      (__attribute__((address_space(3))) void*)(lp), 16, 0, 0)

// Swizzled staging: lane l stages row l>>2 (4 lanes/row -> one 64B segment,
// coalesced) at k-chunk c = (l&3) ^ key(row), key(r) = (r>>1)&3. LDS layout:
// (r,c) at chunkbase + r*32 + (c^key(r))*8 elems. Fragment read (rl,kq) ->
// 16B unit rl*4 + (kq^key(rl)): all 64 distinct, 8-lane groups hit 8 distinct
// bank quads -> conflict-free ds_read_b128 AND coalesced global fetch.

// ---------------------------------------------------------------------------
// Shared relaxed-sync MFMA K-loop (session-verified R3/R4). Templated:
// NF = B-fragment count (4 -> N=128, 2 -> N=64 for ssm half-tiles),
// MF = A-fragment count (4 -> M=128; MF=2 REGRESSED for avm in R11 — doubled
// FETCH + per-tile overhead — kept only for generality, unused).
// 256 threads, 4 waves (2M x 2N), per-wave (MF*16) x (NF*16), BK=64.
// LDS: A triple-buffered (staged 2 tiles ahead) + B double-buffered (1 ahead).
// Per K-tile: all ds_reads up-front, stage B(t+1) (NF loads) + A(t+2) (MF),
// 4 MFMA groups gated by compiler counted lgkmcnt; close with lgkmcnt(0) +
// counted vmcnt(MF) + ONE s_barrier. Requires ntk >= 2.
constexpr int ABUFE = 128 * 64;       // elems per A buffer at MF=4 (16 KB)
constexpr int BBUFE = 128 * 64;       // elems per B buffer at NF=4 (16 KB)
constexpr int MG_LDS = (3 * ABUFE + 2 * BBUFE) * 2;  // 81920 B
constexpr int PJ_LDS = 4 * 8192 * 2;                 // 65536 B (k_projm)

template <int ASTR, int BSTR, int NF = 4, int MF = 4>
__device__ __forceinline__ void mfma_loop128(const __bf16* __restrict__ Abase,
                                             const __bf16* __restrict__ Bbase,
                                             const int ntk,
                                             __bf16* As, __bf16* Bs,
                                             const int wave, const int lane,
                                             f32x4 acc[MF][NF]) {
  constexpr int NH = NF / 2;                        // n per group
  constexpr int MH = MF / 2;                        // m per group
  constexpr int ABE = MF * 2048;                    // elems per A buffer
  const int wr = wave >> 1, wc = wave & 1;          // 2(M) x 2(N) waves
  const int lr = lane >> 2;                         // staging row in chunk
  const int lkx = ((lane & 3) ^ ((lane >> 3) & 3)) * 8;  // staging k offset
  const int rl = lane & 15, kq = lane >> 4;         // frag row / k-quarter
  const int swo = rl * 32 + ((kq ^ ((rl >> 1) & 3)) * 8);

#define VMW_MF()                                                            \
  do {                                                                      \
    if constexpr (MF == 4)                                                  \
      asm volatile("s_waitcnt vmcnt(4)" ::: "memory");                      \
    else                                                                    \
      asm volatile("s_waitcnt vmcnt(2)" ::: "memory");                      \
  } while (0)

  // stage: one 16-row x 32-k chunk per wave per call; ci = i*4 + wave.
#define SA_(i, kt, bsel) do {                                               \
    const int ci_ = (i) * 4 + wave;                                         \
    GLOAD_LDS16(Abase + (size_t)((ci_ >> 1) * 16 + lr) * ASTR               \
                    + (kt) * 64 + (ci_ & 1) * 32 + lkx,                     \
                As + (bsel) * ABE + ci_ * 512);                             \
  } while (0)
#define SB_(j, kt, bsel) do {                                               \
    const int ci_ = (j) * 4 + wave;                                         \
    GLOAD_LDS16(Bbase + (size_t)((ci_ >> 1) * 16 + lr) * BSTR               \
                    + (kt) * 64 + (ci_ & 1) * 32 + lkx,                     \
                Bs + (bsel) * BBUFE + ci_ * 512);                           \
  } while (0)

  // Prologue: A(0), B(0), A(1)  (B(1) staged inside tile 0).
  #pragma unroll
  for (int i = 0; i < MF; ++i) SA_(i, 0, 0);
  #pragma unroll
  for (int j = 0; j < NF; ++j) SB_(j, 0, 0);
  #pragma unroll
  for (int i = 0; i < MF; ++i) SA_(i, 1, 1);
  __builtin_amdgcn_sched_barrier(0);
  VMW_MF();                                         // A(0)+B(0) landed
  __builtin_amdgcn_sched_barrier(0);
  __builtin_amdgcn_s_barrier();

  int cbA = 0;                         // A buffer holding tile t
  for (int t = 0; t < ntk; ++t) {
    const int sbA = (cbA + 2 >= 3) ? cbA - 1 : cbA + 2;  // (cbA+2)%3
    const __bf16* Ac = As + cbA * ABE;
    const __bf16* Bc = Bs + (t & 1) * BBUFE;
    bf16x8 a[MF][2], b[NF][2];
    // --- issue all ds_reads, order a-lo, b-lo, a-hi, b-hi ---
    #pragma unroll
    for (int m = 0; m < MH; ++m)
      #pragma unroll
      for (int kc = 0; kc < 2; ++kc)
        a[m][kc] = *(const bf16x8*)&Ac[((wr * MF + m) * 2 + kc) * 512 + swo];
    #pragma unroll
    for (int n = 0; n < NH; ++n)
      #pragma unroll
      for (int kc = 0; kc < 2; ++kc)
        b[n][kc] = *(const bf16x8*)&Bc[((wc * NF + n) * 2 + kc) * 512 + swo];
    #pragma unroll
    for (int m = MH; m < MF; ++m)
      #pragma unroll
      for (int kc = 0; kc < 2; ++kc)
        a[m][kc] = *(const bf16x8*)&Ac[((wr * MF + m) * 2 + kc) * 512 + swo];
    #pragma unroll
    for (int n = NH; n < NF; ++n)
      #pragma unroll
      for (int kc = 0; kc < 2; ++kc)
        b[n][kc] = *(const bf16x8*)&Bc[((wc * NF + n) * 2 + kc) * 512 + swo];
    // --- issue staging: B for t+1, A for t+2 (order matters for vmcnt) ---
    if (t + 1 < ntk) {
      #pragma unroll
      for (int j = 0; j < NF; ++j) SB_(j, t + 1, (t + 1) & 1);
    }
    if (t + 2 < ntk) {
      #pragma unroll
      for (int i = 0; i < MF; ++i) SA_(i, t + 2, sbA);
    }
    __builtin_amdgcn_sched_barrier(0);
    // --- G1: m-lo x n-lo (compiler counted lgkmcnt gates) ---
    __builtin_amdgcn_s_setprio(1);
    #pragma unroll
    for (int kc = 0; kc < 2; ++kc)
      #pragma unroll
      for (int m = 0; m < MH; ++m)
        #pragma unroll
        for (int n = 0; n < NH; ++n)
          acc[m][n] = __builtin_amdgcn_mfma_f32_16x16x32_bf16(
              a[m][kc], b[n][kc], acc[m][n], 0, 0, 0);
    __builtin_amdgcn_s_setprio(0);
    __builtin_amdgcn_sched_barrier(0);
    // --- G2: m-hi x n-lo ---
    __builtin_amdgcn_s_setprio(1);
    #pragma unroll
    for (int kc = 0; kc < 2; ++kc)
      #pragma unroll
      for (int m = MH; m < MF; ++m)
        #pragma unroll
        for (int n = 0; n < NH; ++n)
          acc[m][n] = __builtin_amdgcn_mfma_f32_16x16x32_bf16(
              a[m][kc], b[n][kc], acc[m][n], 0, 0, 0);
    __builtin_amdgcn_s_setprio(0);
    __builtin_amdgcn_sched_barrier(0);
    // --- G3: m-lo x n-hi ---
    __builtin_amdgcn_s_setprio(1);
    #pragma unroll
    for (int kc = 0; kc < 2; ++kc)
      #pragma unroll
      for (int m = 0; m < MH; ++m)
        #pragma unroll
        for (int n = NH; n < NF; ++n)
          acc[m][n] = __builtin_amdgcn_mfma_f32_16x16x32_bf16(
              a[m][kc], b[n][kc], acc[m][n], 0, 0, 0);
    __builtin_amdgcn_s_setprio(0);
    __builtin_amdgcn_sched_barrier(0);
    // --- G4: m-hi x n-hi ---
    __builtin_amdgcn_s_setprio(1);
    #pragma unroll
    for (int kc = 0; kc < 2; ++kc)
      #pragma unroll
      for (int m = MH; m < MF; ++m)
        #pragma unroll
        for (int n = NH; n < NF; ++n)
          acc[m][n] = __builtin_amdgcn_mfma_f32_16x16x32_bf16(
              a[m][kc], b[n][kc], acc[m][n], 0, 0, 0);
    __builtin_amdgcn_s_setprio(0);
    __builtin_amdgcn_sched_barrier(0);
    // --- tile close: drain my reads (free by now), prove t+1 staged, bar ---
    asm volatile("s_waitcnt lgkmcnt(0)" ::: "memory");
    __builtin_amdgcn_sched_barrier(0);
    if (t + 2 < ntk) {                 // newest MF = SA(t+2); SB(t+1) retired
      VMW_MF();
    } else if (t + 1 < ntk) {          // tail: drain SB(t+1)
      asm volatile("s_waitcnt vmcnt(0)" ::: "memory");
    }
    __builtin_amdgcn_sched_barrier(0);
    __builtin_amdgcn_s_barrier();
    cbA = (cbA + 1 >= 3) ? 0 : cbA + 1;
  }
#undef SA_
#undef SB_
#undef VMW_MF
}

// ---------------------------------------------------------------------------
// Decay tables + zero the TP / STAT accumulators (inside the graph, so each
// replay re-zeroes before k_projm / k_avm atomics).
__global__ __launch_bounds__(256) void k_tables(float* __restrict__ ct,
                                                float* __restrict__ pn,
                                                float* __restrict__ TP,
                                                float* __restrict__ STAT) {
  int idx = blockIdx.x * 256 + threadIdx.x;   // 0 .. H*S-1 (16384)
  int h = idx >> 10, t = idx & 1023;
  double gamma = 1.0 - exp2(-(double)(5 + h));
  double l2g = log2(gamma);
  double r = 1.0 / gamma;
  double rowsum = (exp2(-(double)(t + 1) * l2g) - 1.0) / (r - 1.0);
  ct[idx] = (float)(exp2((double)t * l2g) / sqrt(rowsum));
  pn[idx] = (float)exp2(-(double)t * l2g);
  float4 z4 = {0.f, 0.f, 0.f, 0.f};
  *(float4*)(TP + (size_t)idx * 4) = z4;      // 16384*4 = 65536 floats
  if (idx < BSc * 2) STAT[idx] = 0.f;         // 8192 floats
}

// ---------------------------------------------------------------------------
// fp32 -> bf16 cast, 8 elems/thread; grid.y selects which tensor (fused 3x).
__global__ __launch_bounds__(256) void k_cast83(const float* __restrict__ s0,
                                                const float* __restrict__ s1,
                                                const float* __restrict__ s2,
                                                __bf16* __restrict__ d0,
                                                __bf16* __restrict__ d1,
                                                __bf16* __restrict__ d2) {
  const int y = blockIdx.y;
  const float* src = (y == 0) ? s0 : (y == 1) ? s1 : s2;
  __bf16* dst = (y == 0) ? d0 : (y == 1) ? d1 : d2;
  size_t i = ((size_t)blockIdx.x * 256 + threadIdx.x) * 8;
  float4 a = *(const float4*)(src + i);
  float4 b = *(const float4*)(src + i + 4);
  bf16x8 o;
  o[0] = (__bf16)a.x; o[1] = (__bf16)a.y; o[2] = (__bf16)a.z; o[3] = (__bf16)a.w;
  o[4] = (__bf16)b.x; o[5] = (__bf16)b.y; o[6] = (__bf16)b.z; o[7] = (__bf16)b.w;
  *(bf16x8*)(dst + i) = o;
}

// ---------------------------------------------------------------------------
// Transpose-cast x2: dst[n][k] = (bf16) src[k][n], 2048x2048; z selects wg/wo.
__global__ __launch_bounds__(256) void k_castT2(const float* __restrict__ s0,
                                                const float* __restrict__ s1,
                                                __bf16* __restrict__ d0,
                                                __bf16* __restrict__ d1) {
  __shared__ float t[32][33];
  const int bx = blockIdx.x, by = blockIdx.y;
  const float* src = blockIdx.z ? s1 : s0;
  __bf16* dst = blockIdx.z ? d1 : d0;
  const int tid = threadIdx.x;
  const int lx = tid & 31, ly = tid >> 5;   // 32 x 8
  #pragma unroll
  for (int r = 0; r < 32; r += 8)
    t[ly + r][lx] = src[(size_t)(by * 32 + ly + r) * Dc + bx * 32 + lx];
  __syncthreads();
  #pragma unroll
  for (int r = 0; r < 32; r += 8)
    dst[(size_t)(bx * 32 + ly + r) * Dc + by * 32 + lx] = (__bf16)t[lx][ly + r];
}

// ---------------------------------------------------------------------------
// Per-head transpose-cast of Wh: WhT[h][e][d] = (bf16) Wh[h][d][e].
__global__ __launch_bounds__(256) void k_whT(const float* __restrict__ Wh,
                                             __bf16* __restrict__ WhT) {
  __shared__ float t[32][33];
  const int h = blockIdx.z;
  const int d0 = blockIdx.x * 32, e0 = blockIdx.y * 32;
  const int tid = threadIdx.x;
  const int lx = tid & 31, ly = tid >> 5;
  #pragma unroll
  for (int r = 0; r < 32; r += 8)
    t[ly + r][lx] = Wh[(size_t)h * HDc * HDc + (d0 + ly + r) * HDc + e0 + lx];
  __syncthreads();
  #pragma unroll
  for (int r = 0; r < 32; r += 8)
    WhT[(size_t)h * HDc * HDc + (e0 + ly + r) * HDc + d0 + lx] =
        (__bf16)t[lx][ly + r];
}

// ---------------------------------------------------------------------------
// MFMA projections, SINGLE-STAGE (K=128 fits in LDS). Stage X-panel (32 KB) +
// W-panel (32 KB) once, one vmcnt(0) + one barrier, 128 MFMA/wave straight
// through. 64 KiB LDS -> 2 WGs/CU; 1536 blocks stream 6 rounds/CU.
// z=0: Xb -> Q layout [h][s][b*HD]; z=1: Kb2 -> K layout.
// z=2 (V): k_vt is FUSED here — the 128x128 output tile is transposed
// in-LDS (reusing the staging space, pad 132 -> 2-way conflicts = free) and
// written directly as Vt[(b*16+h)][e][t] with coalesced 16B stores; TP
// column sums accumulate in the same pass (2 atomics/col/block, bf16-rounded
// values = identical semantics to the old k_vt). VB intermediate eliminated.
__global__ __launch_bounds__(256, 2) void k_projm(const __bf16* __restrict__ Xb,
                                                  const __bf16* __restrict__ Kb2,
                                                  const __bf16* __restrict__ Vb2,
                                                  const __bf16* __restrict__ WhT,
                                                  __bf16* __restrict__ Qo,
                                                  __bf16* __restrict__ Ko,
                                                  __bf16* __restrict__ Vt,
                                                  float* __restrict__ TP) {
  extern __shared__ __bf16 lds[];
  __bf16* Xs = lds;                    // 2 x 8192 (kt-major)
  __bf16* Ws = lds + 2 * 8192;         // 2 x 8192
  const int r0 = blockIdx.x * 128;
  const int h = blockIdx.y;
  const int z = blockIdx.z;
  const __bf16* src = (z == 0) ? Xb : (z == 1) ? Kb2 : Vb2;
  const __bf16* wsrc = WhT + (size_t)h * HDc * HDc;
  const int tid = threadIdx.x;
  const int wave = tid >> 6, lane = tid & 63;
  const int wr = wave >> 1, wc = wave & 1;
  const int lr = lane >> 2;
  const int lkx = ((lane & 3) ^ ((lane >> 3) & 3)) * 8;
  const int rl = lane & 15, kq = lane >> 4;
  const int swo = rl * 32 + ((kq ^ ((rl >> 1) & 3)) * 8);
  // stage both K-halves of both operands (same chunk swizzle as the loop)
  #pragma unroll
  for (int kt = 0; kt < 2; ++kt) {
    #pragma unroll
    for (int i = 0; i < 4; ++i) {
      const int ci = i * 4 + wave;
      const int row = (ci >> 1) * 16 + lr;
      const int ko = kt * 64 + (ci & 1) * 32 + lkx;
      GLOAD_LDS16(src + (size_t)(r0 + row) * Dc + h * HDc + ko,
                  Xs + kt * 8192 + ci * 512);
      GLOAD_LDS16(wsrc + (size_t)row * HDc + ko, Ws + kt * 8192 + ci * 512);
    }
  }
  __builtin_amdgcn_sched_barrier(0);
  asm volatile("s_waitcnt vmcnt(0)" ::: "memory");
  __builtin_amdgcn_sched_barrier(0);
  __builtin_amdgcn_s_barrier();
  f32x4 acc[4][4] = {{}};
  #pragma unroll
  for (int kt = 0; kt < 2; ++kt) {
    bf16x8 a[4][2], b[4][2];
    #pragma unroll
    for (int m = 0; m < 4; ++m)
      #pragma unroll
      for (int kc = 0; kc < 2; ++kc)
        a[m][kc] =
            *(const bf16x8*)&Xs[kt * 8192 + ((wr * 4 + m) * 2 + kc) * 512 + swo];
    #pragma unroll
    for (int n = 0; n < 4; ++n)
      #pragma unroll
      for (int kc = 0; kc < 2; ++kc)
        b[n][kc] =
            *(const bf16x8*)&Ws[kt * 8192 + ((wc * 4 + n) * 2 + kc) * 512 + swo];
    #pragma unroll
    for (int kc = 0; kc < 2; ++kc)
      #pragma unroll
      for (int m = 0; m < 4; ++m)
        #pragma unroll
        for (int n = 0; n < 4; ++n)
          acc[m][n] = __builtin_amdgcn_mfma_f32_16x16x32_bf16(
              a[m][kc], b[n][kc], acc[m][n], 0, 0, 0);
  }
  if (z == 2) {
    // ---- fused V transpose + TP sums (replaces k_vt) ----
    __bf16* tl = lds;                  // [128 cols][pad 132 rr] = 33 KB
    __syncthreads();                   // all Xs/Ws reads complete
    #pragma unroll
    for (int mi = 0; mi < 4; ++mi) {
      #pragma unroll
      for (int nj = 0; nj < 4; ++nj) {
        const int col = wc * 64 + nj * 16 + rl;
        const int rrb = wr * 64 + mi * 16 + kq * 4;
        bf16x4 v4;
        v4[0] = (__bf16)acc[mi][nj][0];
        v4[1] = (__bf16)acc[mi][nj][1];
        v4[2] = (__bf16)acc[mi][nj][2];
        v4[3] = (__bf16)acc[mi][nj][3];
        *(bf16x4*)&tl[col * 132 + rrb] = v4;
      }
    }
    __syncthreads();
    const int e = tid >> 1, rh = (tid & 1) * 64;
    const int bh2 = (r0 >> 10) * 16 + h;
    const int jj = (r0 & 1023) >> 7;
    const int sb = r0 & 1023;
    float colsum = 0.f;
    #pragma unroll
    for (int j = 0; j < 8; ++j) {
      bf16x8 v = *(const bf16x8*)&tl[e * 132 + rh + j * 8];
      #pragma unroll
      for (int q = 0; q < 8; ++q) colsum += (float)v[q];
      *(bf16x8*)&Vt[((size_t)bh2 * HDc + e) * Sc + sb + rh + j * 8] = v;
    }
    atomicAdd(&TP[((size_t)bh2 * 8 + jj) * HDc + e], colsum);
  } else {
    __bf16* dst = (z == 0) ? Qo : Ko;
    #pragma unroll
    for (int mi = 0; mi < 4; ++mi) {
      #pragma unroll
      for (int nj = 0; nj < 4; ++nj) {
        const int col = wc * 64 + nj * 16 + rl;
        #pragma unroll
        for (int r = 0; r < 4; ++r) {
          const int row = r0 + wr * 64 + mi * 16 + kq * 4 + r;
          const int s = row & 1023, bb = row >> 10;
          dst[((size_t)(h * Sc + s) * Bc + bb) * HDc + col] =
              (__bf16)acc[mi][nj][r];
        }
      }
    }
  }
}

// ---------------------------------------------------------------------------
// Stage 2: suffix-scan tiles -> SufV[bh][j][e] = sum_{t >= 128*j} V[b,t,h,e].
__global__ __launch_bounds__(128) void k_vscan(const float* __restrict__ T,
                                               float* __restrict__ SufV) {
  const int bh = blockIdx.x;
  const int e = threadIdx.x;
  float acc = 0.f;
  SufV[((size_t)bh * 9 + 8) * HDc + e] = 0.f;
  for (int jj = 7; jj >= 1; --jj) {
    acc += T[((size_t)bh * 8 + jj) * HDc + e];
    SufV[((size_t)bh * 9 + jj) * HDc + e] = acc;
  }
}

// ---------------------------------------------------------------------------
// SS via shared loop (NF=2 half-tiles): A[h][s][t] =
// clamp(|ct[t]*pn[s]*(Q·K^T)/sqrt(128)|,1) for t<=s, 1.0 for t>s in-tile.
// Grid (8,9,16) = 1152 blocks, ONE 128(s)x64(t) half-tile each -> all 256 CUs
// active (R7/R9 grid idled 112 CUs; measured 9% occ). id mod 8 == bx keeps
// XCD K-panel-column specialization.
//   by<8, bx<=by -> tile (r=by, c=bx) half 0
//   by<8, bx> by -> tile (r=bx, c=by) half 1   (mirror pairing)
//   by==8        -> diagonal tile (bx,bx) half 1
__global__ __launch_bounds__(256, 2) void k_ssm(const __bf16* __restrict__ Q,
                                                const __bf16* __restrict__ Kb,
                                                const float* __restrict__ ct,
                                                const float* __restrict__ pn,
                                                __bf16* __restrict__ A) {
  const int bx = blockIdx.x, by = blockIdx.y;
  int r, c, half;
  if (by == 8)       { r = bx; c = bx; half = 1; }
  else if (bx > by)  { r = bx; c = by; half = 1; }
  else               { r = by; c = bx; half = 0; }
  extern __shared__ __bf16 lds[];
  __bf16* As = lds;
  __bf16* Bs = lds + 3 * ABUFE;
  const int h = blockIdx.z;
  const int s0 = r * 128;
  const int t0 = c * 128 + half * 64;
  const int tid = threadIdx.x;
  __bf16* Ah = A + (size_t)h * Sc * Sc;
  const int wave = tid >> 6, lane = tid & 63;
  f32x4 acc[4][2] = {{}};
  mfma_loop128<KQKc, KQKc, 2>(Q + (size_t)(h * Sc + s0) * KQKc,
                              Kb + (size_t)(h * Sc + t0) * KQKc, KQKc / 64,
                              As, Bs, wave, lane, acc);
  const int wr = wave >> 1, wc = wave & 1;
  const int rl = lane & 15, kq = lane >> 4;
  const float rs = 0.088388347648318447f;  // 1/sqrt(128)
  #pragma unroll
  for (int mi = 0; mi < 4; ++mi) {
    #pragma unroll
    for (int nj = 0; nj < 2; ++nj) {
      const int t = t0 + wc * 32 + nj * 16 + rl;
      const float ctv = ct[h * Sc + t] * rs;
      #pragma unroll
      for (int rr = 0; rr < 4; ++rr) {
        const int s = s0 + wr * 64 + mi * 16 + kq * 4 + rr;
        float v = 1.0f;
        if (t <= s) v = fmaxf(fabsf(ctv * pn[h * Sc + s] * acc[mi][nj][rr]), 1.0f);
        Ah[(size_t)s * Sc + t] = (__bf16)v;
      }
    }
  }
}

// ---------------------------------------------------------------------------
// O = A @ V via shared loop, triangular; all-ones region added as fp32 SufV.
// Grid (8,1,64) = 512 blocks = 2 WGs/CU, lid-remap for deterministic balance
// (R10 form, measured 43.5 us; R11's MF=2 equal-length split REGRESSED to
// 52.5 us — doubled FETCH 36->82 MB + doubled per-tile overhead — avm is
// declared structurally limited here).
// Epilogue accumulates GroupNorm stats into STAT via 16-lane shfl reduce +
// 2 atomics per row per wave.
__global__ __launch_bounds__(256, 2) void k_avm(const __bf16* __restrict__ A,
                                                const __bf16* __restrict__ Vt,
                                                const float* __restrict__ SufV,
                                                float* __restrict__ O,
                                                float* __restrict__ STAT) {
  extern __shared__ __bf16 lds[];
  __bf16* As = lds;
  __bf16* Bs = lds + 3 * ABUFE;
  const int lid = (int)blockIdx.z * 8 + (int)blockIdx.x;  // 0..511, x fastest
  const int slot = lid & 255;
  const int bh = slot >> 2;                                // 0..63
  const int itile = (lid < 256) ? (slot & 3) : 7 - (slot & 3);
  const int bb = bh >> 4, h = bh & 15;
  const int s0 = itile * 128;
  const int tid = threadIdx.x;
  const int wave = tid >> 6, lane = tid & 63;
  const int wr = wave >> 1, wc = wave & 1;
  const int rl = lane & 15, kq = lane >> 4;
  f32x4 acc[4][4] = {{}};
  mfma_loop128<Sc, Sc>(A + (size_t)(h * Sc + s0) * Sc,
                       Vt + (size_t)bh * HDc * Sc, (itile + 1) * 2, As, Bs,
                       wave, lane, acc);
  const float* sufr = SufV + ((size_t)bh * 9 + (itile + 1)) * HDc;
  #pragma unroll
  for (int mi = 0; mi < 4; ++mi) {
    #pragma unroll
    for (int r = 0; r < 4; ++r) {
      const int s = s0 + wr * 64 + mi * 16 + kq * 4 + r;
      const size_t orow = (size_t)(bb * Sc + s);
      float vs = 0.f, vq = 0.f;
      #pragma unroll
      for (int nj = 0; nj < 4; ++nj) {
        const int e = wc * 64 + nj * 16 + rl;
        const float v = acc[mi][nj][r] + sufr[e];
        O[orow * Dc + h * HDc + e] = v;
        vs += v;
        vq += v * v;
      }
      #pragma unroll
      for (int m = 1; m < 16; m <<= 1) {
        vs += __shfl_xor(vs, m);
        vq += __shfl_xor(vq, m);
      }
      if (rl == 0) {
        atomicAdd(&STAT[orow * 2], vs);
        atomicAdd(&STAT[orow * 2 + 1], vq);
      }
    }
  }
}

// ---------------------------------------------------------------------------
// bf16 MFMA GEMM via shared loop: C = A @ Bt^T. M=4096, N=2048, K=2048
// (NTK=32). Grid 16(N) x 32(M) = 512 WGs = 2/CU. XCD-chunked swizzle.
// mode 0: Gout = bf16(relu(acc) * groupnorm(Y; STAT, gw, bw))  (gnorm fused:
//         mu/var from STAT one-pass).
// mode 1: Fout = acc (fp32).
__global__ __launch_bounds__(256, 2) void k_mgemm(const __bf16* __restrict__ Ab,
                                                  const __bf16* __restrict__ Bt,
                                                  const float* __restrict__ Y,
                                                  const float* __restrict__ gw,
                                                  const float* __restrict__ bw,
                                                  const float* __restrict__ STAT,
                                                  __bf16* __restrict__ Gout,
                                                  float* __restrict__ Fout,
                                                  int mode) {
  extern __shared__ __bf16 lds[];
  __bf16* As = lds;
  __bf16* Bs = lds + 3 * ABUFE;
  // XCD-chunked swizzle: 512 WGs, 64 consecutive work-ids per XCD ->
  // each XCD owns 4 adjacent A-panels (4 x 0.5MB) x full B sweep.
  int wid = blockIdx.y * gridDim.x + blockIdx.x;
  wid = (wid & 7) * 64 + (wid >> 3);
  const int r0 = (wid >> 4) * 128;    // M block (32)
  const int c0 = (wid & 15) * 128;    // N block (16)
  const int tid = threadIdx.x;
  const int wave = tid >> 6, lane = tid & 63;
  f32x4 acc[4][4] = {{}};
  mfma_loop128<Dc, Dc>(Ab + (size_t)r0 * Dc, Bt + (size_t)c0 * Dc, Dc / 64,
                       As, Bs, wave, lane, acc);
  const int wr = wave >> 1, wc = wave & 1;
  const int rl = lane & 15, kq = lane >> 4;
  if (mode == 0) {
    #pragma unroll
    for (int mi = 0; mi < 4; ++mi) {
      #pragma unroll
      for (int r = 0; r < 4; ++r) {
        const int row = r0 + wr * 64 + mi * 16 + kq * 4 + r;
        const float mu = STAT[(size_t)row * 2] * (1.0f / Dc);
        const float va = STAT[(size_t)row * 2 + 1] * (1.0f / Dc) - mu * mu;
        const float inv = rsqrtf(va + GN_EPS);
        #pragma unroll
        for (int nj = 0; nj < 4; ++nj) {
          const int col = c0 + wc * 64 + nj * 16 + rl;
          const size_t idx = (size_t)row * Dc + col;
          const float yv = (Y[idx] - mu) * inv * gw[col] + bw[col];
          Gout[idx] = (__bf16)(fmaxf(acc[mi][nj][r], 0.f) * yv);
        }
      }
    }
  } else {
    #pragma unroll
    for (int mi = 0; mi < 4; ++mi) {
      #pragma unroll
      for (int nj = 0; nj < 4; ++nj) {
        const int col = c0 + wc * 64 + nj * 16 + rl;
        #pragma unroll
        for (int r = 0; r < 4; ++r) {
          const int row = r0 + wr * 64 + mi * 16 + kq * 4 + r;
          Fout[(size_t)row * Dc + col] = acc[mi][nj][r];
        }
      }
    }
  }
}

// ---------------------------------------------------------------------------
extern "C" void kernel_launch(void* const* d_in, const int* in_sizes, int n_in,
                              void* d_out, int out_size, void* d_ws, size_t ws_size,
                              hipStream_t stream) {
  const float* x  = (const float*)d_in[0];
  const float* k  = (const float*)d_in[1];
  const float* v  = (const float*)d_in[2];
  const float* Wh = (const float*)d_in[3];
  const float* wg = (const float*)d_in[4];
  const float* wo = (const float*)d_in[5];
  const float* gg = (const float*)d_in[6];
  const float* gb = (const float*)d_in[7];
  float* ws = (float*)d_ws;
  __bf16* Q   = (__bf16*)(ws + OFF_Q);
  __bf16* Kp  = (__bf16*)(ws + OFF_K);
  __bf16* Vt  = (__bf16*)(ws + OFF_VT);
  __bf16* A   = (__bf16*)(ws + OFF_A);
  float*  O   = ws + OFF_O;
  float*  CT  = ws + OFF_CT;
  float*  PN  = ws + OFF_PN;
  __bf16* XB  = (__bf16*)(ws + OFF_XB);
  __bf16* WGT = (__bf16*)(ws + OFF_WGT);
  __bf16* WOT = (__bf16*)(ws + OFF_WOT);
  float*  SUF = ws + OFF_SUF;
  float*  TP  = ws + OFF_T;
  __bf16* WHT = (__bf16*)(ws + OFF_WHT);
  float*  STAT= ws + OFF_STAT;
  __bf16* KB2 = (__bf16*)(ws + OFF_KB2);  // aliases A (dead until k_ssm)
  __bf16* VB2 = (__bf16*)(ws + OFF_VB2);  // aliases A second half
  __bf16* G   = (__bf16*)(ws + OFF_Q);    // reuse Q region (dead after k_ssm)

  // one-time opt-in for dynamic LDS (host-side, graph-capture safe)
  static bool attr_done = false;
  if (!attr_done) {
    (void)hipFuncSetAttribute((const void*)k_mgemm,
                              hipFuncAttributeMaxDynamicSharedMemorySize,
                              MG_LDS);
    (void)hipFuncSetAttribute((const void*)k_projm,
                              hipFuncAttributeMaxDynamicSharedMemorySize,
                              PJ_LDS);
    (void)hipFuncSetAttribute((const void*)k_ssm,
                              hipFuncAttributeMaxDynamicSharedMemorySize,
                              MG_LDS);
    (void)hipFuncSetAttribute((const void*)k_avm,
                              hipFuncAttributeMaxDynamicSharedMemorySize,
                              MG_LDS);
    attr_done = true;
  }

  k_tables<<<Hc * Sc / 256, 256, 0, stream>>>(CT, PN, TP, STAT);
  k_cast83<<<dim3((BSc * Dc) / (256 * 8), 3), 256, 0, stream>>>(
      x, k, v, XB, KB2, VB2);
  k_castT2<<<dim3(Dc / 32, Dc / 32, 2), 256, 0, stream>>>(wg, wo, WGT, WOT);
  k_whT<<<dim3(4, 4, Hc), 256, 0, stream>>>(Wh, WHT);
  k_projm<<<dim3(BSc / 128, Hc, 3), 256, PJ_LDS, stream>>>(XB, KB2, VB2, WHT,
                                                           Q, Kp, Vt, TP);
  k_vscan<<<Bc * Hc, 128, 0, stream>>>(TP, SUF);
  k_ssm<<<dim3(8, 9, Hc), 256, MG_LDS, stream>>>(Q, Kp, CT, PN, A);
  k_avm<<<dim3(8, 1, Bc * Hc), 256, MG_LDS, stream>>>(A, Vt, SUF, O, STAT);
  k_mgemm<<<dim3(16, 32), 256, MG_LDS, stream>>>(XB, WGT, O, gg, gb, STAT, G,
                                                 nullptr, 0);
  k_mgemm<<<dim3(16, 32), 256, MG_LDS, stream>>>(G, WOT, nullptr, nullptr,
                                                 nullptr, nullptr, nullptr,
                                                 (float*)d_out, 1);
}

// Round 13
// 342.734 us; speedup vs baseline: 1.0656x; 1.0098x over previous
//
#include <hip/hip_runtime.h>
#include <math.h>

// Problem constants
constexpr int Bc = 4, Sc = 1024, Dc = 2048, HDc = 128, Hc = 16;
constexpr int BSc = Bc * Sc;        // 4096 token rows
constexpr int KQKc = Bc * HDc;      // 512 = batch-concat K dim for SS GEMM
#define GN_EPS 1e-3f

typedef __bf16 bf16x8 __attribute__((ext_vector_type(8)));
typedef __bf16 bf16x4 __attribute__((ext_vector_type(4)));
typedef float f32x4 __attribute__((ext_vector_type(4)));

// Workspace layout (float units)
constexpr size_t OFF_Q   = 0;                                  // bf16 [H][S][512]
constexpr size_t OFF_K   = OFF_Q + (size_t)Hc * Sc * KQKc / 2; // bf16 same
constexpr size_t OFF_VB  = OFF_K + (size_t)Hc * Sc * KQKc / 2; // (dead; layout keep)
constexpr size_t OFF_VT  = OFF_VB + (size_t)BSc * Dc / 2;      // bf16 [BH][128][1024]
constexpr size_t OFF_A   = OFF_VT + (size_t)BSc * Dc / 2;      // bf16 [H][S][S]
constexpr size_t OFF_O   = OFF_A + (size_t)Hc * Sc * Sc / 2;   // fp32 [BS][D]
constexpr size_t OFF_CT  = OFF_O + (size_t)BSc * Dc;           // [H][S]
constexpr size_t OFF_PN  = OFF_CT + (size_t)Hc * Sc;           // [H][S]
constexpr size_t OFF_XB  = OFF_PN + (size_t)Hc * Sc;           // bf16 [BS][D]
constexpr size_t OFF_WGT = OFF_XB + (size_t)BSc * Dc / 2;      // bf16 [D][D] T
constexpr size_t OFF_WOT = OFF_WGT + (size_t)Dc * Dc / 2;      // bf16 [D][D] T
constexpr size_t OFF_SUF = OFF_WOT + (size_t)Dc * Dc / 2;      // fp32 [64][9][128]
constexpr size_t OFF_T   = OFF_SUF + (size_t)64 * 9 * HDc;     // fp32 [64][8][128]
constexpr size_t OFF_WHT = OFF_T + (size_t)64 * 8 * HDc;       // bf16 [H][128][128]
constexpr size_t OFF_STAT= OFF_WHT + (size_t)Hc * HDc * HDc / 2; // fp32 [BS][2]
// G (bf16 [BS][D]) reuses the Q buffer (dead after k_ssm).

#define GLOAD_LDS16(gp, lp)                                               \
  __builtin_amdgcn_global_load_lds(                                       \
      (const __attribute__((address_space(1))) void*)(gp),                \
      (__attribute__((address_space(3))) void*)(lp), 16, 0, 0)

// Swizzled staging: lane l stages row l>>2 (4 lanes/row -> one 64B segment,
// coalesced) at k-chunk c = (l&3) ^ key(row), key(r) = (r>>1)&3. LDS layout:
// (r,c) at chunkbase + r*32 + (c^key(r))*8 elems. Fragment read (rl,kq) ->
// 16B unit rl*4 + (kq^key(rl)): all 64 distinct, 8-lane groups hit 8 distinct
// bank quads -> conflict-free ds_read_b128 AND coalesced global fetch.

// ---------------------------------------------------------------------------
// Shared relaxed-sync MFMA K-loop (session-verified R3/R4). Templated:
// NF = B-fragment count (4 -> N=128, 2 -> N=64 for ssm half-tiles),
// MF = A-fragment count (4 -> M=128; MF=2 REGRESSED for avm in R11).
// 256 threads, 4 waves (2M x 2N), per-wave (MF*16) x (NF*16), BK=64.
// LDS: A triple-buffered (staged 2 tiles ahead) + B double-buffered (1 ahead).
// Per K-tile: all ds_reads up-front, stage B(t+1) (NF loads) + A(t+2) (MF),
// 4 MFMA groups gated by compiler counted lgkmcnt; close with lgkmcnt(0) +
// counted vmcnt(MF) + ONE s_barrier. Requires ntk >= 2.
constexpr int ABUFE = 128 * 64;       // elems per A buffer at MF=4 (16 KB)
constexpr int BBUFE = 128 * 64;       // elems per B buffer at NF=4 (16 KB)
constexpr int MG_LDS = (3 * ABUFE + 2 * BBUFE) * 2;  // 81920 B
constexpr int PJ_LDS = 4 * 8192 * 2;                 // 65536 B (k_projm)

template <int ASTR, int BSTR, int NF = 4, int MF = 4>
__device__ __forceinline__ void mfma_loop128(const __bf16* __restrict__ Abase,
                                             const __bf16* __restrict__ Bbase,
                                             const int ntk,
                                             __bf16* As, __bf16* Bs,
                                             const int wave, const int lane,
                                             f32x4 acc[MF][NF]) {
  constexpr int NH = NF / 2;                        // n per group
  constexpr int MH = MF / 2;                        // m per group
  constexpr int ABE = MF * 2048;                    // elems per A buffer
  const int wr = wave >> 1, wc = wave & 1;          // 2(M) x 2(N) waves
  const int lr = lane >> 2;                         // staging row in chunk
  const int lkx = ((lane & 3) ^ ((lane >> 3) & 3)) * 8;  // staging k offset
  const int rl = lane & 15, kq = lane >> 4;         // frag row / k-quarter
  const int swo = rl * 32 + ((kq ^ ((rl >> 1) & 3)) * 8);

#define VMW_MF()                                                            \
  do {                                                                      \
    if constexpr (MF == 4)                                                  \
      asm volatile("s_waitcnt vmcnt(4)" ::: "memory");                      \
    else                                                                    \
      asm volatile("s_waitcnt vmcnt(2)" ::: "memory");                      \
  } while (0)

  // stage: one 16-row x 32-k chunk per wave per call; ci = i*4 + wave.
#define SA_(i, kt, bsel) do {                                               \
    const int ci_ = (i) * 4 + wave;                                         \
    GLOAD_LDS16(Abase + (size_t)((ci_ >> 1) * 16 + lr) * ASTR               \
                    + (kt) * 64 + (ci_ & 1) * 32 + lkx,                     \
                As + (bsel) * ABE + ci_ * 512);                             \
  } while (0)
#define SB_(j, kt, bsel) do {                                               \
    const int ci_ = (j) * 4 + wave;                                         \
    GLOAD_LDS16(Bbase + (size_t)((ci_ >> 1) * 16 + lr) * BSTR               \
                    + (kt) * 64 + (ci_ & 1) * 32 + lkx,                     \
                Bs + (bsel) * BBUFE + ci_ * 512);                           \
  } while (0)

  // Prologue: A(0), B(0), A(1)  (B(1) staged inside tile 0).
  #pragma unroll
  for (int i = 0; i < MF; ++i) SA_(i, 0, 0);
  #pragma unroll
  for (int j = 0; j < NF; ++j) SB_(j, 0, 0);
  #pragma unroll
  for (int i = 0; i < MF; ++i) SA_(i, 1, 1);
  __builtin_amdgcn_sched_barrier(0);
  VMW_MF();                                         // A(0)+B(0) landed
  __builtin_amdgcn_sched_barrier(0);
  __builtin_amdgcn_s_barrier();

  int cbA = 0;                         // A buffer holding tile t
  for (int t = 0; t < ntk; ++t) {
    const int sbA = (cbA + 2 >= 3) ? cbA - 1 : cbA + 2;  // (cbA+2)%3
    const __bf16* Ac = As + cbA * ABE;
    const __bf16* Bc = Bs + (t & 1) * BBUFE;
    bf16x8 a[MF][2], b[NF][2];
    // --- issue all ds_reads, order a-lo, b-lo, a-hi, b-hi ---
    #pragma unroll
    for (int m = 0; m < MH; ++m)
      #pragma unroll
      for (int kc = 0; kc < 2; ++kc)
        a[m][kc] = *(const bf16x8*)&Ac[((wr * MF + m) * 2 + kc) * 512 + swo];
    #pragma unroll
    for (int n = 0; n < NH; ++n)
      #pragma unroll
      for (int kc = 0; kc < 2; ++kc)
        b[n][kc] = *(const bf16x8*)&Bc[((wc * NF + n) * 2 + kc) * 512 + swo];
    #pragma unroll
    for (int m = MH; m < MF; ++m)
      #pragma unroll
      for (int kc = 0; kc < 2; ++kc)
        a[m][kc] = *(const bf16x8*)&Ac[((wr * MF + m) * 2 + kc) * 512 + swo];
    #pragma unroll
    for (int n = NH; n < NF; ++n)
      #pragma unroll
      for (int kc = 0; kc < 2; ++kc)
        b[n][kc] = *(const bf16x8*)&Bc[((wc * NF + n) * 2 + kc) * 512 + swo];
    // --- issue staging: B for t+1, A for t+2 (order matters for vmcnt) ---
    if (t + 1 < ntk) {
      #pragma unroll
      for (int j = 0; j < NF; ++j) SB_(j, t + 1, (t + 1) & 1);
    }
    if (t + 2 < ntk) {
      #pragma unroll
      for (int i = 0; i < MF; ++i) SA_(i, t + 2, sbA);
    }
    __builtin_amdgcn_sched_barrier(0);
    // --- G1: m-lo x n-lo (compiler counted lgkmcnt gates) ---
    __builtin_amdgcn_s_setprio(1);
    #pragma unroll
    for (int kc = 0; kc < 2; ++kc)
      #pragma unroll
      for (int m = 0; m < MH; ++m)
        #pragma unroll
        for (int n = 0; n < NH; ++n)
          acc[m][n] = __builtin_amdgcn_mfma_f32_16x16x32_bf16(
              a[m][kc], b[n][kc], acc[m][n], 0, 0, 0);
    __builtin_amdgcn_s_setprio(0);
    __builtin_amdgcn_sched_barrier(0);
    // --- G2: m-hi x n-lo ---
    __builtin_amdgcn_s_setprio(1);
    #pragma unroll
    for (int kc = 0; kc < 2; ++kc)
      #pragma unroll
      for (int m = MH; m < MF; ++m)
        #pragma unroll
        for (int n = 0; n < NH; ++n)
          acc[m][n] = __builtin_amdgcn_mfma_f32_16x16x32_bf16(
              a[m][kc], b[n][kc], acc[m][n], 0, 0, 0);
    __builtin_amdgcn_s_setprio(0);
    __builtin_amdgcn_sched_barrier(0);
    // --- G3: m-lo x n-hi ---
    __builtin_amdgcn_s_setprio(1);
    #pragma unroll
    for (int kc = 0; kc < 2; ++kc)
      #pragma unroll
      for (int m = 0; m < MH; ++m)
        #pragma unroll
        for (int n = NH; n < NF; ++n)
          acc[m][n] = __builtin_amdgcn_mfma_f32_16x16x32_bf16(
              a[m][kc], b[n][kc], acc[m][n], 0, 0, 0);
    __builtin_amdgcn_s_setprio(0);
    __builtin_amdgcn_sched_barrier(0);
    // --- G4: m-hi x n-hi ---
    __builtin_amdgcn_s_setprio(1);
    #pragma unroll
    for (int kc = 0; kc < 2; ++kc)
      #pragma unroll
      for (int m = MH; m < MF; ++m)
        #pragma unroll
        for (int n = NH; n < NF; ++n)
          acc[m][n] = __builtin_amdgcn_mfma_f32_16x16x32_bf16(
              a[m][kc], b[n][kc], acc[m][n], 0, 0, 0);
    __builtin_amdgcn_s_setprio(0);
    __builtin_amdgcn_sched_barrier(0);
    // --- tile close: drain my reads (free by now), prove t+1 staged, bar ---
    asm volatile("s_waitcnt lgkmcnt(0)" ::: "memory");
    __builtin_amdgcn_sched_barrier(0);
    if (t + 2 < ntk) {                 // newest MF = SA(t+2); SB(t+1) retired
      VMW_MF();
    } else if (t + 1 < ntk) {          // tail: drain SB(t+1)
      asm volatile("s_waitcnt vmcnt(0)" ::: "memory");
    }
    __builtin_amdgcn_sched_barrier(0);
    __builtin_amdgcn_s_barrier();
    cbA = (cbA + 1 >= 3) ? 0 : cbA + 1;
  }
#undef SA_
#undef SB_
#undef VMW_MF
}

// ---------------------------------------------------------------------------
// Decay tables + zero the TP / STAT accumulators (inside the graph, so each
// replay re-zeroes before k_projm / k_avm atomics).
__global__ __launch_bounds__(256) void k_tables(float* __restrict__ ct,
                                                float* __restrict__ pn,
                                                float* __restrict__ TP,
                                                float* __restrict__ STAT) {
  int idx = blockIdx.x * 256 + threadIdx.x;   // 0 .. H*S-1 (16384)
  int h = idx >> 10, t = idx & 1023;
  double gamma = 1.0 - exp2(-(double)(5 + h));
  double l2g = log2(gamma);
  double r = 1.0 / gamma;
  double rowsum = (exp2(-(double)(t + 1) * l2g) - 1.0) / (r - 1.0);
  ct[idx] = (float)(exp2((double)t * l2g) / sqrt(rowsum));
  pn[idx] = (float)exp2(-(double)t * l2g);
  float4 z4 = {0.f, 0.f, 0.f, 0.f};
  *(float4*)(TP + (size_t)idx * 4) = z4;      // 16384*4 = 65536 floats
  if (idx < BSc * 2) STAT[idx] = 0.f;         // 8192 floats
}

// ---------------------------------------------------------------------------
// fp32 -> bf16 cast, 8 elems/thread (x -> XB only; k/v casts are fused into
// k_projm's reg-staged path, eliminating the 64 MB KB2/VB2 HBM bounce).
__global__ __launch_bounds__(256) void k_cast8(const float* __restrict__ src,
                                               __bf16* __restrict__ dst) {
  size_t i = ((size_t)blockIdx.x * 256 + threadIdx.x) * 8;
  float4 a = *(const float4*)(src + i);
  float4 b = *(const float4*)(src + i + 4);
  bf16x8 o;
  o[0] = (__bf16)a.x; o[1] = (__bf16)a.y; o[2] = (__bf16)a.z; o[3] = (__bf16)a.w;
  o[4] = (__bf16)b.x; o[5] = (__bf16)b.y; o[6] = (__bf16)b.z; o[7] = (__bf16)b.w;
  *(bf16x8*)(dst + i) = o;
}

// ---------------------------------------------------------------------------
// Transpose-cast x2: dst[n][k] = (bf16) src[k][n], 2048x2048; z selects wg/wo.
__global__ __launch_bounds__(256) void k_castT2(const float* __restrict__ s0,
                                                const float* __restrict__ s1,
                                                __bf16* __restrict__ d0,
                                                __bf16* __restrict__ d1) {
  __shared__ float t[32][33];
  const int bx = blockIdx.x, by = blockIdx.y;
  const float* src = blockIdx.z ? s1 : s0;
  __bf16* dst = blockIdx.z ? d1 : d0;
  const int tid = threadIdx.x;
  const int lx = tid & 31, ly = tid >> 5;   // 32 x 8
  #pragma unroll
  for (int r = 0; r < 32; r += 8)
    t[ly + r][lx] = src[(size_t)(by * 32 + ly + r) * Dc + bx * 32 + lx];
  __syncthreads();
  #pragma unroll
  for (int r = 0; r < 32; r += 8)
    dst[(size_t)(bx * 32 + ly + r) * Dc + by * 32 + lx] = (__bf16)t[lx][ly + r];
}

// ---------------------------------------------------------------------------
// Per-head transpose-cast of Wh: WhT[h][e][d] = (bf16) Wh[h][d][e].
__global__ __launch_bounds__(256) void k_whT(const float* __restrict__ Wh,
                                             __bf16* __restrict__ WhT) {
  __shared__ float t[32][33];
  const int h = blockIdx.z;
  const int d0 = blockIdx.x * 32, e0 = blockIdx.y * 32;
  const int tid = threadIdx.x;
  const int lx = tid & 31, ly = tid >> 5;
  #pragma unroll
  for (int r = 0; r < 32; r += 8)
    t[ly + r][lx] = Wh[(size_t)h * HDc * HDc + (d0 + ly + r) * HDc + e0 + lx];
  __syncthreads();
  #pragma unroll
  for (int r = 0; r < 32; r += 8)
    WhT[(size_t)h * HDc * HDc + (e0 + ly + r) * HDc + d0 + lx] =
        (__bf16)t[lx][ly + r];
}

// ---------------------------------------------------------------------------
// MFMA projections, SINGLE-STAGE (K=128 fits in LDS). 64 KiB LDS -> 2 WGs/CU;
// 1536 blocks stream 6 rounds/CU.
// z=0: XB (bf16, via global_load_lds) -> Q layout [h][s][b*HD].
// z=1: raw fp32 k, REG-STAGED (2x float4 -> bf16x8 cvt -> ds_write_b128 at
//      base+lane*8, the exact address global_load_lds would write; same
//      rounding as the old cast83 path -> bit-identical MFMA inputs).
// z=2: raw fp32 v, reg-staged likewise; k_vt fused: output tile transposed
//      in-LDS (pad 132) -> Vt[(b*16+h)][e][t] 16B stores + TP column sums.
__global__ __launch_bounds__(256, 2) void k_projm(const __bf16* __restrict__ Xb,
                                                  const float* __restrict__ kf,
                                                  const float* __restrict__ vf,
                                                  const __bf16* __restrict__ WhT,
                                                  __bf16* __restrict__ Qo,
                                                  __bf16* __restrict__ Ko,
                                                  __bf16* __restrict__ Vt,
                                                  float* __restrict__ TP) {
  extern __shared__ __bf16 lds[];
  __bf16* Xs = lds;                    // 2 x 8192 (kt-major)
  __bf16* Ws = lds + 2 * 8192;         // 2 x 8192
  const int r0 = blockIdx.x * 128;
  const int h = blockIdx.y;
  const int z = blockIdx.z;
  const __bf16* wsrc = WhT + (size_t)h * HDc * HDc;
  const int tid = threadIdx.x;
  const int wave = tid >> 6, lane = tid & 63;
  const int wr = wave >> 1, wc = wave & 1;
  const int lr = lane >> 2;
  const int lkx = ((lane & 3) ^ ((lane >> 3) & 3)) * 8;
  const int rl = lane & 15, kq = lane >> 4;
  const int swo = rl * 32 + ((kq ^ ((rl >> 1) & 3)) * 8);
  // W-panel always via global_load_lds
  #pragma unroll
  for (int kt = 0; kt < 2; ++kt) {
    #pragma unroll
    for (int i = 0; i < 4; ++i) {
      const int ci = i * 4 + wave;
      const int row = (ci >> 1) * 16 + lr;
      const int ko = kt * 64 + (ci & 1) * 32 + lkx;
      GLOAD_LDS16(wsrc + (size_t)row * HDc + ko, Ws + kt * 8192 + ci * 512);
    }
  }
  if (z == 0) {
    #pragma unroll
    for (int kt = 0; kt < 2; ++kt) {
      #pragma unroll
      for (int i = 0; i < 4; ++i) {
        const int ci = i * 4 + wave;
        const int row = (ci >> 1) * 16 + lr;
        const int ko = kt * 64 + (ci & 1) * 32 + lkx;
        GLOAD_LDS16(Xb + (size_t)(r0 + row) * Dc + h * HDc + ko,
                    Xs + kt * 8192 + ci * 512);
      }
    }
  } else {
    const float* fsrc = (z == 1) ? kf : vf;
    #pragma unroll
    for (int kt = 0; kt < 2; ++kt) {
      #pragma unroll
      for (int i = 0; i < 4; ++i) {
        const int ci = i * 4 + wave;
        const int row = (ci >> 1) * 16 + lr;
        const int ko = kt * 64 + (ci & 1) * 32 + lkx;
        const float* gp = fsrc + (size_t)(r0 + row) * Dc + h * HDc + ko;
        f32x4 f0 = *(const f32x4*)gp;
        f32x4 f1 = *(const f32x4*)(gp + 4);
        bf16x8 o;
        o[0] = (__bf16)f0[0]; o[1] = (__bf16)f0[1];
        o[2] = (__bf16)f0[2]; o[3] = (__bf16)f0[3];
        o[4] = (__bf16)f1[0]; o[5] = (__bf16)f1[1];
        o[6] = (__bf16)f1[2]; o[7] = (__bf16)f1[3];
        *(bf16x8*)&Xs[kt * 8192 + ci * 512 + lane * 8] = o;
      }
    }
  }
  __builtin_amdgcn_sched_barrier(0);
  asm volatile("s_waitcnt vmcnt(0) lgkmcnt(0)" ::: "memory");
  __builtin_amdgcn_sched_barrier(0);
  __builtin_amdgcn_s_barrier();
  f32x4 acc[4][4] = {{}};
  #pragma unroll
  for (int kt = 0; kt < 2; ++kt) {
    bf16x8 a[4][2], b[4][2];
    #pragma unroll
    for (int m = 0; m < 4; ++m)
      #pragma unroll
      for (int kc = 0; kc < 2; ++kc)
        a[m][kc] =
            *(const bf16x8*)&Xs[kt * 8192 + ((wr * 4 + m) * 2 + kc) * 512 + swo];
    #pragma unroll
    for (int n = 0; n < 4; ++n)
      #pragma unroll
      for (int kc = 0; kc < 2; ++kc)
        b[n][kc] =
            *(const bf16x8*)&Ws[kt * 8192 + ((wc * 4 + n) * 2 + kc) * 512 + swo];
    #pragma unroll
    for (int kc = 0; kc < 2; ++kc)
      #pragma unroll
      for (int m = 0; m < 4; ++m)
        #pragma unroll
        for (int n = 0; n < 4; ++n)
          acc[m][n] = __builtin_amdgcn_mfma_f32_16x16x32_bf16(
              a[m][kc], b[n][kc], acc[m][n], 0, 0, 0);
  }
  if (z == 2) {
    // ---- fused V transpose + TP sums (replaces k_vt) ----
    __bf16* tl = lds;                  // [128 cols][pad 132 rr] = 33 KB
    __syncthreads();                   // all Xs/Ws reads complete
    #pragma unroll
    for (int mi = 0; mi < 4; ++mi) {
      #pragma unroll
      for (int nj = 0; nj < 4; ++nj) {
        const int col = wc * 64 + nj * 16 + rl;
        const int rrb = wr * 64 + mi * 16 + kq * 4;
        bf16x4 v4;
        v4[0] = (__bf16)acc[mi][nj][0];
        v4[1] = (__bf16)acc[mi][nj][1];
        v4[2] = (__bf16)acc[mi][nj][2];
        v4[3] = (__bf16)acc[mi][nj][3];
        *(bf16x4*)&tl[col * 132 + rrb] = v4;
      }
    }
    __syncthreads();
    const int e = tid >> 1, rh = (tid & 1) * 64;
    const int bh2 = (r0 >> 10) * 16 + h;
    const int jj = (r0 & 1023) >> 7;
    const int sb = r0 & 1023;
    float colsum = 0.f;
    #pragma unroll
    for (int j = 0; j < 8; ++j) {
      bf16x8 v = *(const bf16x8*)&tl[e * 132 + rh + j * 8];
      #pragma unroll
      for (int q = 0; q < 8; ++q) colsum += (float)v[q];
      *(bf16x8*)&Vt[((size_t)bh2 * HDc + e) * Sc + sb + rh + j * 8] = v;
    }
    atomicAdd(&TP[((size_t)bh2 * 8 + jj) * HDc + e], colsum);
  } else {
    __bf16* dst = (z == 0) ? Qo : Ko;
    #pragma unroll
    for (int mi = 0; mi < 4; ++mi) {
      #pragma unroll
      for (int nj = 0; nj < 4; ++nj) {
        const int col = wc * 64 + nj * 16 + rl;
        #pragma unroll
        for (int r = 0; r < 4; ++r) {
          const int row = r0 + wr * 64 + mi * 16 + kq * 4 + r;
          const int s = row & 1023, bb = row >> 10;
          dst[((size_t)(h * Sc + s) * Bc + bb) * HDc + col] =
              (__bf16)acc[mi][nj][r];
        }
      }
    }
  }
}

// ---------------------------------------------------------------------------
// Stage 2: suffix-scan tiles -> SufV[bh][j][e] = sum_{t >= 128*j} V[b,t,h,e].
__global__ __launch_bounds__(128) void k_vscan(const float* __restrict__ T,
                                               float* __restrict__ SufV) {
  const int bh = blockIdx.x;
  const int e = threadIdx.x;
  float acc = 0.f;
  SufV[((size_t)bh * 9 + 8) * HDc + e] = 0.f;
  for (int jj = 7; jj >= 1; --jj) {
    acc += T[((size_t)bh * 8 + jj) * HDc + e];
    SufV[((size_t)bh * 9 + jj) * HDc + e] = acc;
  }
}

// ---------------------------------------------------------------------------
// SS via shared loop (NF=2 half-tiles): A[h][s][t] =
// clamp(|ct[t]*pn[s]*(Q·K^T)/sqrt(128)|,1) for t<=s, 1.0 for t>s in-tile.
// Grid (8,9,16) = 1152 blocks, ONE 128(s)x64(t) half-tile each -> all 256 CUs
// active. id mod 8 == bx keeps XCD K-panel-column specialization.
//   by<8, bx<=by -> tile (r=by, c=bx) half 0
//   by<8, bx> by -> tile (r=bx, c=by) half 1   (mirror pairing)
//   by==8        -> diagonal tile (bx,bx) half 1
__global__ __launch_bounds__(256, 2) void k_ssm(const __bf16* __restrict__ Q,
                                                const __bf16* __restrict__ Kb,
                                                const float* __restrict__ ct,
                                                const float* __restrict__ pn,
                                                __bf16* __restrict__ A) {
  const int bx = blockIdx.x, by = blockIdx.y;
  int r, c, half;
  if (by == 8)       { r = bx; c = bx; half = 1; }
  else if (bx > by)  { r = bx; c = by; half = 1; }
  else               { r = by; c = bx; half = 0; }
  extern __shared__ __bf16 lds[];
  __bf16* As = lds;
  __bf16* Bs = lds + 3 * ABUFE;
  const int h = blockIdx.z;
  const int s0 = r * 128;
  const int t0 = c * 128 + half * 64;
  const int tid = threadIdx.x;
  __bf16* Ah = A + (size_t)h * Sc * Sc;
  const int wave = tid >> 6, lane = tid & 63;
  f32x4 acc[4][2] = {{}};
  mfma_loop128<KQKc, KQKc, 2>(Q + (size_t)(h * Sc + s0) * KQKc,
                              Kb + (size_t)(h * Sc + t0) * KQKc, KQKc / 64,
                              As, Bs, wave, lane, acc);
  const int wr = wave >> 1, wc = wave & 1;
  const int rl = lane & 15, kq = lane >> 4;
  const float rs = 0.088388347648318447f;  // 1/sqrt(128)
  #pragma unroll
  for (int mi = 0; mi < 4; ++mi) {
    #pragma unroll
    for (int nj = 0; nj < 2; ++nj) {
      const int t = t0 + wc * 32 + nj * 16 + rl;
      const float ctv = ct[h * Sc + t] * rs;
      #pragma unroll
      for (int rr = 0; rr < 4; ++rr) {
        const int s = s0 + wr * 64 + mi * 16 + kq * 4 + rr;
        float v = 1.0f;
        if (t <= s) v = fmaxf(fabsf(ctv * pn[h * Sc + s] * acc[mi][nj][rr]), 1.0f);
        Ah[(size_t)s * Sc + t] = (__bf16)v;
      }
    }
  }
}

// ---------------------------------------------------------------------------
// O = A @ V via shared loop, triangular; all-ones region added as fp32 SufV.
// Grid (8,1,64) = 512 blocks = 2 WGs/CU, lid-remap for deterministic balance
// (R10 form; R11's MF=2 split regressed — avm structurally limited here).
// Epilogue accumulates GroupNorm stats into STAT via 16-lane shfl reduce +
// 2 atomics per row per wave.
__global__ __launch_bounds__(256, 2) void k_avm(const __bf16* __restrict__ A,
                                                const __bf16* __restrict__ Vt,
                                                const float* __restrict__ SufV,
                                                float* __restrict__ O,
                                                float* __restrict__ STAT) {
  extern __shared__ __bf16 lds[];
  __bf16* As = lds;
  __bf16* Bs = lds + 3 * ABUFE;
  const int lid = (int)blockIdx.z * 8 + (int)blockIdx.x;  // 0..511, x fastest
  const int slot = lid & 255;
  const int bh = slot >> 2;                                // 0..63
  const int itile = (lid < 256) ? (slot & 3) : 7 - (slot & 3);
  const int bb = bh >> 4, h = bh & 15;
  const int s0 = itile * 128;
  const int tid = threadIdx.x;
  const int wave = tid >> 6, lane = tid & 63;
  const int wr = wave >> 1, wc = wave & 1;
  const int rl = lane & 15, kq = lane >> 4;
  f32x4 acc[4][4] = {{}};
  mfma_loop128<Sc, Sc>(A + (size_t)(h * Sc + s0) * Sc,
                       Vt + (size_t)bh * HDc * Sc, (itile + 1) * 2, As, Bs,
                       wave, lane, acc);
  const float* sufr = SufV + ((size_t)bh * 9 + (itile + 1)) * HDc;
  #pragma unroll
  for (int mi = 0; mi < 4; ++mi) {
    #pragma unroll
    for (int r = 0; r < 4; ++r) {
      const int s = s0 + wr * 64 + mi * 16 + kq * 4 + r;
      const size_t orow = (size_t)(bb * Sc + s);
      float vs = 0.f, vq = 0.f;
      #pragma unroll
      for (int nj = 0; nj < 4; ++nj) {
        const int e = wc * 64 + nj * 16 + rl;
        const float v = acc[mi][nj][r] + sufr[e];
        O[orow * Dc + h * HDc + e] = v;
        vs += v;
        vq += v * v;
      }
      #pragma unroll
      for (int m = 1; m < 16; m <<= 1) {
        vs += __shfl_xor(vs, m);
        vq += __shfl_xor(vq, m);
      }
      if (rl == 0) {
        atomicAdd(&STAT[orow * 2], vs);
        atomicAdd(&STAT[orow * 2 + 1], vq);
      }
    }
  }
}

// ---------------------------------------------------------------------------
// bf16 MFMA GEMM via shared loop: C = A @ Bt^T. M=4096, N=2048, K=2048
// (NTK=32). Grid 16(N) x 32(M) = 512 WGs = 2/CU. XCD-chunked swizzle.
// mode 0: Gout = bf16(relu(acc) * groupnorm(Y; STAT, gw, bw)).
// mode 1: Fout = acc (fp32).
__global__ __launch_bounds__(256, 2) void k_mgemm(const __bf16* __restrict__ Ab,
                                                  const __bf16* __restrict__ Bt,
                                                  const float* __restrict__ Y,
                                                  const float* __restrict__ gw,
                                                  const float* __restrict__ bw,
                                                  const float* __restrict__ STAT,
                                                  __bf16* __restrict__ Gout,
                                                  float* __restrict__ Fout,
                                                  int mode) {
  extern __shared__ __bf16 lds[];
  __bf16* As = lds;
  __bf16* Bs = lds + 3 * ABUFE;
  // XCD-chunked swizzle: 512 WGs, 64 consecutive work-ids per XCD ->
  // each XCD owns 4 adjacent A-panels (4 x 0.5MB) x full B sweep.
  int wid = blockIdx.y * gridDim.x + blockIdx.x;
  wid = (wid & 7) * 64 + (wid >> 3);
  const int r0 = (wid >> 4) * 128;    // M block (32)
  const int c0 = (wid & 15) * 128;    // N block (16)
  const int tid = threadIdx.x;
  const int wave = tid >> 6, lane = tid & 63;
  f32x4 acc[4][4] = {{}};
  mfma_loop128<Dc, Dc>(Ab + (size_t)r0 * Dc, Bt + (size_t)c0 * Dc, Dc / 64,
                       As, Bs, wave, lane, acc);
  const int wr = wave >> 1, wc = wave & 1;
  const int rl = lane & 15, kq = lane >> 4;
  if (mode == 0) {
    #pragma unroll
    for (int mi = 0; mi < 4; ++mi) {
      #pragma unroll
      for (int r = 0; r < 4; ++r) {
        const int row = r0 + wr * 64 + mi * 16 + kq * 4 + r;
        const float mu = STAT[(size_t)row * 2] * (1.0f / Dc);
        const float va = STAT[(size_t)row * 2 + 1] * (1.0f / Dc) - mu * mu;
        const float inv = rsqrtf(va + GN_EPS);
        #pragma unroll
        for (int nj = 0; nj < 4; ++nj) {
          const int col = c0 + wc * 64 + nj * 16 + rl;
          const size_t idx = (size_t)row * Dc + col;
          const float yv = (Y[idx] - mu) * inv * gw[col] + bw[col];
          Gout[idx] = (__bf16)(fmaxf(acc[mi][nj][r], 0.f) * yv);
        }
      }
    }
  } else {
    #pragma unroll
    for (int mi = 0; mi < 4; ++mi) {
      #pragma unroll
      for (int nj = 0; nj < 4; ++nj) {
        const int col = c0 + wc * 64 + nj * 16 + rl;
        #pragma unroll
        for (int r = 0; r < 4; ++r) {
          const int row = r0 + wr * 64 + mi * 16 + kq * 4 + r;
          Fout[(size_t)row * Dc + col] = acc[mi][nj][r];
        }
      }
    }
  }
}

// ---------------------------------------------------------------------------
extern "C" void kernel_launch(void* const* d_in, const int* in_sizes, int n_in,
                              void* d_out, int out_size, void* d_ws, size_t ws_size,
                              hipStream_t stream) {
  const float* x  = (const float*)d_in[0];
  const float* k  = (const float*)d_in[1];
  const float* v  = (const float*)d_in[2];
  const float* Wh = (const float*)d_in[3];
  const float* wg = (const float*)d_in[4];
  const float* wo = (const float*)d_in[5];
  const float* gg = (const float*)d_in[6];
  const float* gb = (const float*)d_in[7];
  float* ws = (float*)d_ws;
  __bf16* Q   = (__bf16*)(ws + OFF_Q);
  __bf16* Kp  = (__bf16*)(ws + OFF_K);
  __bf16* Vt  = (__bf16*)(ws + OFF_VT);
  __bf16* A   = (__bf16*)(ws + OFF_A);
  float*  O   = ws + OFF_O;
  float*  CT  = ws + OFF_CT;
  float*  PN  = ws + OFF_PN;
  __bf16* XB  = (__bf16*)(ws + OFF_XB);
  __bf16* WGT = (__bf16*)(ws + OFF_WGT);
  __bf16* WOT = (__bf16*)(ws + OFF_WOT);
  float*  SUF = ws + OFF_SUF;
  float*  TP  = ws + OFF_T;
  __bf16* WHT = (__bf16*)(ws + OFF_WHT);
  float*  STAT= ws + OFF_STAT;
  __bf16* G   = (__bf16*)(ws + OFF_Q);    // reuse Q region (dead after k_ssm)

  // one-time opt-in for dynamic LDS (host-side, graph-capture safe)
  static bool attr_done = false;
  if (!attr_done) {
    (void)hipFuncSetAttribute((const void*)k_mgemm,
                              hipFuncAttributeMaxDynamicSharedMemorySize,
                              MG_LDS);
    (void)hipFuncSetAttribute((const void*)k_projm,
                              hipFuncAttributeMaxDynamicSharedMemorySize,
                              PJ_LDS);
    (void)hipFuncSetAttribute((const void*)k_ssm,
                              hipFuncAttributeMaxDynamicSharedMemorySize,
                              MG_LDS);
    (void)hipFuncSetAttribute((const void*)k_avm,
                              hipFuncAttributeMaxDynamicSharedMemorySize,
                              MG_LDS);
    attr_done = true;
  }

  k_tables<<<Hc * Sc / 256, 256, 0, stream>>>(CT, PN, TP, STAT);
  k_cast8<<<(BSc * Dc) / (256 * 8), 256, 0, stream>>>(x, XB);
  k_castT2<<<dim3(Dc / 32, Dc / 32, 2), 256, 0, stream>>>(wg, wo, WGT, WOT);
  k_whT<<<dim3(4, 4, Hc), 256, 0, stream>>>(Wh, WHT);
  k_projm<<<dim3(BSc / 128, Hc, 3), 256, PJ_LDS, stream>>>(XB, k, v, WHT,
                                                           Q, Kp, Vt, TP);
  k_vscan<<<Bc * Hc, 128, 0, stream>>>(TP, SUF);
  k_ssm<<<dim3(8, 9, Hc), 256, MG_LDS, stream>>>(Q, Kp, CT, PN, A);
  k_avm<<<dim3(8, 1, Bc * Hc), 256, MG_LDS, stream>>>(A, Vt, SUF, O, STAT);
  k_mgemm<<<dim3(16, 32), 256, MG_LDS, stream>>>(XB, WGT, O, gg, gb, STAT, G,
                                                 nullptr, 0);
  k_mgemm<<<dim3(16, 32), 256, MG_LDS, stream>>>(G, WOT, nullptr, nullptr,
                                                 nullptr, nullptr, nullptr,
                                                 (float*)d_out, 1);
}

// Round 14
// 328.137 us; speedup vs baseline: 1.1130x; 1.0445x over previous
//
#include <hip/hip_runtime.h>
#include <math.h>

// Problem constants
constexpr int Bc = 4, Sc = 1024, Dc = 2048, HDc = 128, Hc = 16;
constexpr int BSc = Bc * Sc;        // 4096 token rows
constexpr int KQKc = Bc * HDc;      // 512 = batch-concat K dim for SS GEMM
#define GN_EPS 1e-3f

typedef __bf16 bf16x8 __attribute__((ext_vector_type(8)));
typedef __bf16 bf16x4 __attribute__((ext_vector_type(4)));
typedef float f32x4 __attribute__((ext_vector_type(4)));

// Workspace layout (float units)
constexpr size_t OFF_Q   = 0;                                  // bf16 [H][S][512]
constexpr size_t OFF_K   = OFF_Q + (size_t)Hc * Sc * KQKc / 2; // bf16 same
constexpr size_t OFF_VB  = OFF_K + (size_t)Hc * Sc * KQKc / 2; // (dead; layout keep)
constexpr size_t OFF_VT  = OFF_VB + (size_t)BSc * Dc / 2;      // bf16 [BH][128][1024]
constexpr size_t OFF_A   = OFF_VT + (size_t)BSc * Dc / 2;      // bf16 [H][S][S]
constexpr size_t OFF_O   = OFF_A + (size_t)Hc * Sc * Sc / 2;   // bf16 [BS][D] (was fp32)
constexpr size_t OFF_CT  = OFF_O + (size_t)BSc * Dc;           // [H][S]
constexpr size_t OFF_PN  = OFF_CT + (size_t)Hc * Sc;           // [H][S]
constexpr size_t OFF_XB  = OFF_PN + (size_t)Hc * Sc;           // bf16 [BS][D]
constexpr size_t OFF_WGT = OFF_XB + (size_t)BSc * Dc / 2;      // bf16 [D][D] T
constexpr size_t OFF_WOT = OFF_WGT + (size_t)Dc * Dc / 2;      // bf16 [D][D] T
constexpr size_t OFF_SUF = OFF_WOT + (size_t)Dc * Dc / 2;      // (dead; layout keep)
constexpr size_t OFF_T   = OFF_SUF + (size_t)64 * 9 * HDc;     // fp32 [64][8][128]
constexpr size_t OFF_WHT = OFF_T + (size_t)64 * 8 * HDc;       // bf16 [H][128][128]
constexpr size_t OFF_STAT= OFF_WHT + (size_t)Hc * HDc * HDc / 2; // fp32 [BS][2]
// G (bf16 [BS][D]) reuses the Q buffer (dead after k_ssm).

#define GLOAD_LDS16(gp, lp)                                               \
  __builtin_amdgcn_global_load_lds(                                       \
      (const __attribute__((address_space(1))) void*)(gp),                \
      (__attribute__((address_space(3))) void*)(lp), 16, 0, 0)

// Swizzled staging: lane l stages row l>>2 (4 lanes/row -> one 64B segment,
// coalesced) at k-chunk c = (l&3) ^ key(row), key(r) = (r>>1)&3. LDS layout:
// (r,c) at chunkbase + r*32 + (c^key(r))*8 elems. Fragment read (rl,kq) ->
// 16B unit rl*4 + (kq^key(rl)): all 64 distinct, 8-lane groups hit 8 distinct
// bank quads -> conflict-free ds_read_b128 AND coalesced global fetch.

// ---------------------------------------------------------------------------
// Shared relaxed-sync MFMA K-loop (session-verified R3/R4). Templated:
// NF = B-fragment count (4 -> N=128, 2 -> N=64 for ssm half-tiles),
// MF = A-fragment count (4 -> M=128; MF=2 REGRESSED for avm in R11).
// 256 threads, 4 waves (2M x 2N), per-wave (MF*16) x (NF*16), BK=64.
// LDS: A triple-buffered (staged 2 tiles ahead) + B double-buffered (1 ahead).
// Per K-tile: all ds_reads up-front, stage B(t+1) (NF loads) + A(t+2) (MF),
// 4 MFMA groups gated by compiler counted lgkmcnt; close with lgkmcnt(0) +
// counted vmcnt(MF) + ONE s_barrier. Requires ntk >= 2.
constexpr int ABUFE = 128 * 64;       // elems per A buffer at MF=4 (16 KB)
constexpr int BBUFE = 128 * 64;       // elems per B buffer at NF=4 (16 KB)
constexpr int MG_LDS = (3 * ABUFE + 2 * BBUFE) * 2;  // 81920 B
constexpr int PJ_LDS = 4 * 8192 * 2;                 // 65536 B (k_projm)

template <int ASTR, int BSTR, int NF = 4, int MF = 4>
__device__ __forceinline__ void mfma_loop128(const __bf16* __restrict__ Abase,
                                             const __bf16* __restrict__ Bbase,
                                             const int ntk,
                                             __bf16* As, __bf16* Bs,
                                             const int wave, const int lane,
                                             f32x4 acc[MF][NF]) {
  constexpr int NH = NF / 2;                        // n per group
  constexpr int MH = MF / 2;                        // m per group
  constexpr int ABE = MF * 2048;                    // elems per A buffer
  const int wr = wave >> 1, wc = wave & 1;          // 2(M) x 2(N) waves
  const int lr = lane >> 2;                         // staging row in chunk
  const int lkx = ((lane & 3) ^ ((lane >> 3) & 3)) * 8;  // staging k offset
  const int rl = lane & 15, kq = lane >> 4;         // frag row / k-quarter
  const int swo = rl * 32 + ((kq ^ ((rl >> 1) & 3)) * 8);

#define VMW_MF()                                                            \
  do {                                                                      \
    if constexpr (MF == 4)                                                  \
      asm volatile("s_waitcnt vmcnt(4)" ::: "memory");                      \
    else                                                                    \
      asm volatile("s_waitcnt vmcnt(2)" ::: "memory");                      \
  } while (0)

  // stage: one 16-row x 32-k chunk per wave per call; ci = i*4 + wave.
#define SA_(i, kt, bsel) do {                                               \
    const int ci_ = (i) * 4 + wave;                                         \
    GLOAD_LDS16(Abase + (size_t)((ci_ >> 1) * 16 + lr) * ASTR               \
                    + (kt) * 64 + (ci_ & 1) * 32 + lkx,                     \
                As + (bsel) * ABE + ci_ * 512);                             \
  } while (0)
#define SB_(j, kt, bsel) do {                                               \
    const int ci_ = (j) * 4 + wave;                                         \
    GLOAD_LDS16(Bbase + (size_t)((ci_ >> 1) * 16 + lr) * BSTR               \
                    + (kt) * 64 + (ci_ & 1) * 32 + lkx,                     \
                Bs + (bsel) * BBUFE + ci_ * 512);                           \
  } while (0)

  // Prologue: A(0), B(0), A(1)  (B(1) staged inside tile 0).
  #pragma unroll
  for (int i = 0; i < MF; ++i) SA_(i, 0, 0);
  #pragma unroll
  for (int j = 0; j < NF; ++j) SB_(j, 0, 0);
  #pragma unroll
  for (int i = 0; i < MF; ++i) SA_(i, 1, 1);
  __builtin_amdgcn_sched_barrier(0);
  VMW_MF();                                         // A(0)+B(0) landed
  __builtin_amdgcn_sched_barrier(0);
  __builtin_amdgcn_s_barrier();

  int cbA = 0;                         // A buffer holding tile t
  for (int t = 0; t < ntk; ++t) {
    const int sbA = (cbA + 2 >= 3) ? cbA - 1 : cbA + 2;  // (cbA+2)%3
    const __bf16* Ac = As + cbA * ABE;
    const __bf16* Bc = Bs + (t & 1) * BBUFE;
    bf16x8 a[MF][2], b[NF][2];
    // --- issue all ds_reads, order a-lo, b-lo, a-hi, b-hi ---
    #pragma unroll
    for (int m = 0; m < MH; ++m)
      #pragma unroll
      for (int kc = 0; kc < 2; ++kc)
        a[m][kc] = *(const bf16x8*)&Ac[((wr * MF + m) * 2 + kc) * 512 + swo];
    #pragma unroll
    for (int n = 0; n < NH; ++n)
      #pragma unroll
      for (int kc = 0; kc < 2; ++kc)
        b[n][kc] = *(const bf16x8*)&Bc[((wc * NF + n) * 2 + kc) * 512 + swo];
    #pragma unroll
    for (int m = MH; m < MF; ++m)
      #pragma unroll
      for (int kc = 0; kc < 2; ++kc)
        a[m][kc] = *(const bf16x8*)&Ac[((wr * MF + m) * 2 + kc) * 512 + swo];
    #pragma unroll
    for (int n = NH; n < NF; ++n)
      #pragma unroll
      for (int kc = 0; kc < 2; ++kc)
        b[n][kc] = *(const bf16x8*)&Bc[((wc * NF + n) * 2 + kc) * 512 + swo];
    // --- issue staging: B for t+1, A for t+2 (order matters for vmcnt) ---
    if (t + 1 < ntk) {
      #pragma unroll
      for (int j = 0; j < NF; ++j) SB_(j, t + 1, (t + 1) & 1);
    }
    if (t + 2 < ntk) {
      #pragma unroll
      for (int i = 0; i < MF; ++i) SA_(i, t + 2, sbA);
    }
    __builtin_amdgcn_sched_barrier(0);
    // --- G1: m-lo x n-lo (compiler counted lgkmcnt gates) ---
    __builtin_amdgcn_s_setprio(1);
    #pragma unroll
    for (int kc = 0; kc < 2; ++kc)
      #pragma unroll
      for (int m = 0; m < MH; ++m)
        #pragma unroll
        for (int n = 0; n < NH; ++n)
          acc[m][n] = __builtin_amdgcn_mfma_f32_16x16x32_bf16(
              a[m][kc], b[n][kc], acc[m][n], 0, 0, 0);
    __builtin_amdgcn_s_setprio(0);
    __builtin_amdgcn_sched_barrier(0);
    // --- G2: m-hi x n-lo ---
    __builtin_amdgcn_s_setprio(1);
    #pragma unroll
    for (int kc = 0; kc < 2; ++kc)
      #pragma unroll
      for (int m = MH; m < MF; ++m)
        #pragma unroll
        for (int n = 0; n < NH; ++n)
          acc[m][n] = __builtin_amdgcn_mfma_f32_16x16x32_bf16(
              a[m][kc], b[n][kc], acc[m][n], 0, 0, 0);
    __builtin_amdgcn_s_setprio(0);
    __builtin_amdgcn_sched_barrier(0);
    // --- G3: m-lo x n-hi ---
    __builtin_amdgcn_s_setprio(1);
    #pragma unroll
    for (int kc = 0; kc < 2; ++kc)
      #pragma unroll
      for (int m = 0; m < MH; ++m)
        #pragma unroll
        for (int n = NH; n < NF; ++n)
          acc[m][n] = __builtin_amdgcn_mfma_f32_16x16x32_bf16(
              a[m][kc], b[n][kc], acc[m][n], 0, 0, 0);
    __builtin_amdgcn_s_setprio(0);
    __builtin_amdgcn_sched_barrier(0);
    // --- G4: m-hi x n-hi ---
    __builtin_amdgcn_s_setprio(1);
    #pragma unroll
    for (int kc = 0; kc < 2; ++kc)
      #pragma unroll
      for (int m = MH; m < MF; ++m)
        #pragma unroll
        for (int n = NH; n < NF; ++n)
          acc[m][n] = __builtin_amdgcn_mfma_f32_16x16x32_bf16(
              a[m][kc], b[n][kc], acc[m][n], 0, 0, 0);
    __builtin_amdgcn_s_setprio(0);
    __builtin_amdgcn_sched_barrier(0);
    // --- tile close: drain my reads (free by now), prove t+1 staged, bar ---
    asm volatile("s_waitcnt lgkmcnt(0)" ::: "memory");
    __builtin_amdgcn_sched_barrier(0);
    if (t + 2 < ntk) {                 // newest MF = SA(t+2); SB(t+1) retired
      VMW_MF();
    } else if (t + 1 < ntk) {          // tail: drain SB(t+1)
      asm volatile("s_waitcnt vmcnt(0)" ::: "memory");
    }
    __builtin_amdgcn_sched_barrier(0);
    __builtin_amdgcn_s_barrier();
    cbA = (cbA + 1 >= 3) ? 0 : cbA + 1;
  }
#undef SA_
#undef SB_
#undef VMW_MF
}

// ---------------------------------------------------------------------------
// fp32 -> bf16 cast (x -> XB), 8 elems/thread; blocks 0..63 ALSO compute the
// decay tables + zero the TP/STAT accumulators (folds old k_tables; stream
// order keeps TP/STAT zeroed before k_projm / k_avm atomics).
__global__ __launch_bounds__(256) void k_cast8t(const float* __restrict__ src,
                                                __bf16* __restrict__ dst,
                                                float* __restrict__ ct,
                                                float* __restrict__ pn,
                                                float* __restrict__ TP,
                                                float* __restrict__ STAT) {
  size_t i = ((size_t)blockIdx.x * 256 + threadIdx.x) * 8;
  float4 a = *(const float4*)(src + i);
  float4 b = *(const float4*)(src + i + 4);
  bf16x8 o;
  o[0] = (__bf16)a.x; o[1] = (__bf16)a.y; o[2] = (__bf16)a.z; o[3] = (__bf16)a.w;
  o[4] = (__bf16)b.x; o[5] = (__bf16)b.y; o[6] = (__bf16)b.z; o[7] = (__bf16)b.w;
  *(bf16x8*)(dst + i) = o;
  if (blockIdx.x < 64) {
    int idx = blockIdx.x * 256 + threadIdx.x;   // 0 .. H*S-1 (16384)
    int h = idx >> 10, t = idx & 1023;
    double gamma = 1.0 - exp2(-(double)(5 + h));
    double l2g = log2(gamma);
    double r = 1.0 / gamma;
    double rowsum = (exp2(-(double)(t + 1) * l2g) - 1.0) / (r - 1.0);
    ct[idx] = (float)(exp2((double)t * l2g) / sqrt(rowsum));
    pn[idx] = (float)exp2(-(double)t * l2g);
    float4 z4 = {0.f, 0.f, 0.f, 0.f};
    *(float4*)(TP + (size_t)idx * 4) = z4;      // 16384*4 = 65536 floats
    if (idx < BSc * 2) STAT[idx] = 0.f;         // 8192 floats
  }
}

// ---------------------------------------------------------------------------
// Transpose-cast x2: dst[n][k] = (bf16) src[k][n], 2048x2048; z selects wg/wo.
__global__ __launch_bounds__(256) void k_castT2(const float* __restrict__ s0,
                                                const float* __restrict__ s1,
                                                __bf16* __restrict__ d0,
                                                __bf16* __restrict__ d1) {
  __shared__ float t[32][33];
  const int bx = blockIdx.x, by = blockIdx.y;
  const float* src = blockIdx.z ? s1 : s0;
  __bf16* dst = blockIdx.z ? d1 : d0;
  const int tid = threadIdx.x;
  const int lx = tid & 31, ly = tid >> 5;   // 32 x 8
  #pragma unroll
  for (int r = 0; r < 32; r += 8)
    t[ly + r][lx] = src[(size_t)(by * 32 + ly + r) * Dc + bx * 32 + lx];
  __syncthreads();
  #pragma unroll
  for (int r = 0; r < 32; r += 8)
    dst[(size_t)(bx * 32 + ly + r) * Dc + by * 32 + lx] = (__bf16)t[lx][ly + r];
}

// ---------------------------------------------------------------------------
// Per-head transpose-cast of Wh: WhT[h][e][d] = (bf16) Wh[h][d][e].
__global__ __launch_bounds__(256) void k_whT(const float* __restrict__ Wh,
                                             __bf16* __restrict__ WhT) {
  __shared__ float t[32][33];
  const int h = blockIdx.z;
  const int d0 = blockIdx.x * 32, e0 = blockIdx.y * 32;
  const int tid = threadIdx.x;
  const int lx = tid & 31, ly = tid >> 5;
  #pragma unroll
  for (int r = 0; r < 32; r += 8)
    t[ly + r][lx] = Wh[(size_t)h * HDc * HDc + (d0 + ly + r) * HDc + e0 + lx];
  __syncthreads();
  #pragma unroll
  for (int r = 0; r < 32; r += 8)
    WhT[(size_t)h * HDc * HDc + (e0 + ly + r) * HDc + d0 + lx] =
        (__bf16)t[lx][ly + r];
}

// ---------------------------------------------------------------------------
// MFMA projections, SINGLE-STAGE (K=128 fits in LDS). 64 KiB LDS -> 2 WGs/CU;
// 1536 blocks stream 6 rounds/CU.
// z=0: XB (bf16, via global_load_lds) -> Q layout [h][s][b*HD].
// z=1: raw fp32 k, REG-STAGED (2x float4 -> bf16x8 cvt -> ds_write_b128 at
//      base+lane*8, the exact address global_load_lds would write).
// z=2: raw fp32 v, reg-staged likewise; k_vt fused: output tile transposed
//      in-LDS (pad 132) -> Vt[(b*16+h)][e][t] 16B stores + TP column sums.
__global__ __launch_bounds__(256, 2) void k_projm(const __bf16* __restrict__ Xb,
                                                  const float* __restrict__ kf,
                                                  const float* __restrict__ vf,
                                                  const __bf16* __restrict__ WhT,
                                                  __bf16* __restrict__ Qo,
                                                  __bf16* __restrict__ Ko,
                                                  __bf16* __restrict__ Vt,
                                                  float* __restrict__ TP) {
  extern __shared__ __bf16 lds[];
  __bf16* Xs = lds;                    // 2 x 8192 (kt-major)
  __bf16* Ws = lds + 2 * 8192;         // 2 x 8192
  const int r0 = blockIdx.x * 128;
  const int h = blockIdx.y;
  const int z = blockIdx.z;
  const __bf16* wsrc = WhT + (size_t)h * HDc * HDc;
  const int tid = threadIdx.x;
  const int wave = tid >> 6, lane = tid & 63;
  const int wr = wave >> 1, wc = wave & 1;
  const int lr = lane >> 2;
  const int lkx = ((lane & 3) ^ ((lane >> 3) & 3)) * 8;
  const int rl = lane & 15, kq = lane >> 4;
  const int swo = rl * 32 + ((kq ^ ((rl >> 1) & 3)) * 8);
  // W-panel always via global_load_lds
  #pragma unroll
  for (int kt = 0; kt < 2; ++kt) {
    #pragma unroll
    for (int i = 0; i < 4; ++i) {
      const int ci = i * 4 + wave;
      const int row = (ci >> 1) * 16 + lr;
      const int ko = kt * 64 + (ci & 1) * 32 + lkx;
      GLOAD_LDS16(wsrc + (size_t)row * HDc + ko, Ws + kt * 8192 + ci * 512);
    }
  }
  if (z == 0) {
    #pragma unroll
    for (int kt = 0; kt < 2; ++kt) {
      #pragma unroll
      for (int i = 0; i < 4; ++i) {
        const int ci = i * 4 + wave;
        const int row = (ci >> 1) * 16 + lr;
        const int ko = kt * 64 + (ci & 1) * 32 + lkx;
        GLOAD_LDS16(Xb + (size_t)(r0 + row) * Dc + h * HDc + ko,
                    Xs + kt * 8192 + ci * 512);
      }
    }
  } else {
    const float* fsrc = (z == 1) ? kf : vf;
    #pragma unroll
    for (int kt = 0; kt < 2; ++kt) {
      #pragma unroll
      for (int i = 0; i < 4; ++i) {
        const int ci = i * 4 + wave;
        const int row = (ci >> 1) * 16 + lr;
        const int ko = kt * 64 + (ci & 1) * 32 + lkx;
        const float* gp = fsrc + (size_t)(r0 + row) * Dc + h * HDc + ko;
        f32x4 f0 = *(const f32x4*)gp;
        f32x4 f1 = *(const f32x4*)(gp + 4);
        bf16x8 o;
        o[0] = (__bf16)f0[0]; o[1] = (__bf16)f0[1];
        o[2] = (__bf16)f0[2]; o[3] = (__bf16)f0[3];
        o[4] = (__bf16)f1[0]; o[5] = (__bf16)f1[1];
        o[6] = (__bf16)f1[2]; o[7] = (__bf16)f1[3];
        *(bf16x8*)&Xs[kt * 8192 + ci * 512 + lane * 8] = o;
      }
    }
  }
  __builtin_amdgcn_sched_barrier(0);
  asm volatile("s_waitcnt vmcnt(0) lgkmcnt(0)" ::: "memory");
  __builtin_amdgcn_sched_barrier(0);
  __builtin_amdgcn_s_barrier();
  f32x4 acc[4][4] = {{}};
  #pragma unroll
  for (int kt = 0; kt < 2; ++kt) {
    bf16x8 a[4][2], b[4][2];
    #pragma unroll
    for (int m = 0; m < 4; ++m)
      #pragma unroll
      for (int kc = 0; kc < 2; ++kc)
        a[m][kc] =
            *(const bf16x8*)&Xs[kt * 8192 + ((wr * 4 + m) * 2 + kc) * 512 + swo];
    #pragma unroll
    for (int n = 0; n < 4; ++n)
      #pragma unroll
      for (int kc = 0; kc < 2; ++kc)
        b[n][kc] =
            *(const bf16x8*)&Ws[kt * 8192 + ((wc * 4 + n) * 2 + kc) * 512 + swo];
    #pragma unroll
    for (int kc = 0; kc < 2; ++kc)
      #pragma unroll
      for (int m = 0; m < 4; ++m)
        #pragma unroll
        for (int n = 0; n < 4; ++n)
          acc[m][n] = __builtin_amdgcn_mfma_f32_16x16x32_bf16(
              a[m][kc], b[n][kc], acc[m][n], 0, 0, 0);
  }
  if (z == 2) {
    // ---- fused V transpose + TP sums (replaces k_vt) ----
    __bf16* tl = lds;                  // [128 cols][pad 132 rr] = 33 KB
    __syncthreads();                   // all Xs/Ws reads complete
    #pragma unroll
    for (int mi = 0; mi < 4; ++mi) {
      #pragma unroll
      for (int nj = 0; nj < 4; ++nj) {
        const int col = wc * 64 + nj * 16 + rl;
        const int rrb = wr * 64 + mi * 16 + kq * 4;
        bf16x4 v4;
        v4[0] = (__bf16)acc[mi][nj][0];
        v4[1] = (__bf16)acc[mi][nj][1];
        v4[2] = (__bf16)acc[mi][nj][2];
        v4[3] = (__bf16)acc[mi][nj][3];
        *(bf16x4*)&tl[col * 132 + rrb] = v4;
      }
    }
    __syncthreads();
    const int e = tid >> 1, rh = (tid & 1) * 64;
    const int bh2 = (r0 >> 10) * 16 + h;
    const int jj = (r0 & 1023) >> 7;
    const int sb = r0 & 1023;
    float colsum = 0.f;
    #pragma unroll
    for (int j = 0; j < 8; ++j) {
      bf16x8 v = *(const bf16x8*)&tl[e * 132 + rh + j * 8];
      #pragma unroll
      for (int q = 0; q < 8; ++q) colsum += (float)v[q];
      *(bf16x8*)&Vt[((size_t)bh2 * HDc + e) * Sc + sb + rh + j * 8] = v;
    }
    atomicAdd(&TP[((size_t)bh2 * 8 + jj) * HDc + e], colsum);
  } else {
    __bf16* dst = (z == 0) ? Qo : Ko;
    #pragma unroll
    for (int mi = 0; mi < 4; ++mi) {
      #pragma unroll
      for (int nj = 0; nj < 4; ++nj) {
        const int col = wc * 64 + nj * 16 + rl;
        #pragma unroll
        for (int r = 0; r < 4; ++r) {
          const int row = r0 + wr * 64 + mi * 16 + kq * 4 + r;
          const int s = row & 1023, bb = row >> 10;
          dst[((size_t)(h * Sc + s) * Bc + bb) * HDc + col] =
              (__bf16)acc[mi][nj][r];
        }
      }
    }
  }
}

// ---------------------------------------------------------------------------
// SS via shared loop (NF=2 half-tiles): A[h][s][t] =
// clamp(|ct[t]*pn[s]*(Q·K^T)/sqrt(128)|,1) for t<=s, 1.0 for t>s in-tile.
// Grid (8,9,16) = 1152 blocks, ONE 128(s)x64(t) half-tile each -> all 256 CUs
// active. id mod 8 == bx keeps XCD K-panel-column specialization.
//   by<8, bx<=by -> tile (r=by, c=bx) half 0
//   by<8, bx> by -> tile (r=bx, c=by) half 1   (mirror pairing)
//   by==8        -> diagonal tile (bx,bx) half 1
__global__ __launch_bounds__(256, 2) void k_ssm(const __bf16* __restrict__ Q,
                                                const __bf16* __restrict__ Kb,
                                                const float* __restrict__ ct,
                                                const float* __restrict__ pn,
                                                __bf16* __restrict__ A) {
  const int bx = blockIdx.x, by = blockIdx.y;
  int r, c, half;
  if (by == 8)       { r = bx; c = bx; half = 1; }
  else if (bx > by)  { r = bx; c = by; half = 1; }
  else               { r = by; c = bx; half = 0; }
  extern __shared__ __bf16 lds[];
  __bf16* As = lds;
  __bf16* Bs = lds + 3 * ABUFE;
  const int h = blockIdx.z;
  const int s0 = r * 128;
  const int t0 = c * 128 + half * 64;
  const int tid = threadIdx.x;
  __bf16* Ah = A + (size_t)h * Sc * Sc;
  const int wave = tid >> 6, lane = tid & 63;
  f32x4 acc[4][2] = {{}};
  mfma_loop128<KQKc, KQKc, 2>(Q + (size_t)(h * Sc + s0) * KQKc,
                              Kb + (size_t)(h * Sc + t0) * KQKc, KQKc / 64,
                              As, Bs, wave, lane, acc);
  const int wr = wave >> 1, wc = wave & 1;
  const int rl = lane & 15, kq = lane >> 4;
  const float rs = 0.088388347648318447f;  // 1/sqrt(128)
  #pragma unroll
  for (int mi = 0; mi < 4; ++mi) {
    #pragma unroll
    for (int nj = 0; nj < 2; ++nj) {
      const int t = t0 + wc * 32 + nj * 16 + rl;
      const float ctv = ct[h * Sc + t] * rs;
      #pragma unroll
      for (int rr = 0; rr < 4; ++rr) {
        const int s = s0 + wr * 64 + mi * 16 + kq * 4 + rr;
        float v = 1.0f;
        if (t <= s) v = fmaxf(fabsf(ctv * pn[h * Sc + s] * acc[mi][nj][rr]), 1.0f);
        Ah[(size_t)s * Sc + t] = (__bf16)v;
      }
    }
  }
}

// ---------------------------------------------------------------------------
// O = A @ V via shared loop, triangular; all-ones region added via per-thread
// suffix sums computed DIRECTLY from TP (k_vscan folded in: 4 x (7-itile)
// scalar L2 reads per thread, held in registers — no LDS, budget is exactly
// 80 KB for 2 WGs/CU). O is stored bf16 (STAT stays fp32 pre-rounding).
// Grid (8,1,64) = 512 blocks = 2 WGs/CU, lid-remap for deterministic balance.
// Epilogue accumulates GroupNorm stats into STAT via 16-lane shfl reduce +
// 2 atomics per row per wave.
__global__ __launch_bounds__(256, 2) void k_avm(const __bf16* __restrict__ A,
                                                const __bf16* __restrict__ Vt,
                                                const float* __restrict__ TP,
                                                __bf16* __restrict__ O,
                                                float* __restrict__ STAT) {
  extern __shared__ __bf16 lds[];
  __bf16* As = lds;
  __bf16* Bs = lds + 3 * ABUFE;
  const int lid = (int)blockIdx.z * 8 + (int)blockIdx.x;  // 0..511, x fastest
  const int slot = lid & 255;
  const int bh = slot >> 2;                                // 0..63
  const int itile = (lid < 256) ? (slot & 3) : 7 - (slot & 3);
  const int bb = bh >> 4, h = bh & 15;
  const int s0 = itile * 128;
  const int tid = threadIdx.x;
  const int wave = tid >> 6, lane = tid & 63;
  const int wr = wave >> 1, wc = wave & 1;
  const int rl = lane & 15, kq = lane >> 4;
  // per-thread suffix sums (replaces k_vscan + SufV buffer)
  float suf4[4];
  #pragma unroll
  for (int nj = 0; nj < 4; ++nj) {
    const int e = wc * 64 + nj * 16 + rl;
    float s = 0.f;
    for (int jj = itile + 1; jj < 8; ++jj)
      s += TP[((size_t)bh * 8 + jj) * HDc + e];
    suf4[nj] = s;
  }
  f32x4 acc[4][4] = {{}};
  mfma_loop128<Sc, Sc>(A + (size_t)(h * Sc + s0) * Sc,
                       Vt + (size_t)bh * HDc * Sc, (itile + 1) * 2, As, Bs,
                       wave, lane, acc);
  #pragma unroll
  for (int mi = 0; mi < 4; ++mi) {
    #pragma unroll
    for (int r = 0; r < 4; ++r) {
      const int s = s0 + wr * 64 + mi * 16 + kq * 4 + r;
      const size_t orow = (size_t)(bb * Sc + s);
      float vs = 0.f, vq = 0.f;
      #pragma unroll
      for (int nj = 0; nj < 4; ++nj) {
        const int e = wc * 64 + nj * 16 + rl;
        const float v = acc[mi][nj][r] + suf4[nj];
        O[orow * Dc + h * HDc + e] = (__bf16)v;
        vs += v;
        vq += v * v;
      }
      #pragma unroll
      for (int m = 1; m < 16; m <<= 1) {
        vs += __shfl_xor(vs, m);
        vq += __shfl_xor(vq, m);
      }
      if (rl == 0) {
        atomicAdd(&STAT[orow * 2], vs);
        atomicAdd(&STAT[orow * 2 + 1], vq);
      }
    }
  }
}

// ---------------------------------------------------------------------------
// bf16 MFMA GEMM via shared loop: C = A @ Bt^T. M=4096, N=2048, K=2048
// (NTK=32). Grid 16(N) x 32(M) = 512 WGs = 2/CU. XCD-chunked swizzle.
// mode 0: Gout = bf16(relu(acc) * groupnorm(Y bf16; STAT fp32, gw, bw)).
// mode 1: Fout = acc (fp32).
__global__ __launch_bounds__(256, 2) void k_mgemm(const __bf16* __restrict__ Ab,
                                                  const __bf16* __restrict__ Bt,
                                                  const __bf16* __restrict__ Y,
                                                  const float* __restrict__ gw,
                                                  const float* __restrict__ bw,
                                                  const float* __restrict__ STAT,
                                                  __bf16* __restrict__ Gout,
                                                  float* __restrict__ Fout,
                                                  int mode) {
  extern __shared__ __bf16 lds[];
  __bf16* As = lds;
  __bf16* Bs = lds + 3 * ABUFE;
  // XCD-chunked swizzle: 512 WGs, 64 consecutive work-ids per XCD ->
  // each XCD owns 4 adjacent A-panels (4 x 0.5MB) x full B sweep.
  int wid = blockIdx.y * gridDim.x + blockIdx.x;
  wid = (wid & 7) * 64 + (wid >> 3);
  const int r0 = (wid >> 4) * 128;    // M block (32)
  const int c0 = (wid & 15) * 128;    // N block (16)
  const int tid = threadIdx.x;
  const int wave = tid >> 6, lane = tid & 63;
  f32x4 acc[4][4] = {{}};
  mfma_loop128<Dc, Dc>(Ab + (size_t)r0 * Dc, Bt + (size_t)c0 * Dc, Dc / 64,
                       As, Bs, wave, lane, acc);
  const int wr = wave >> 1, wc = wave & 1;
  const int rl = lane & 15, kq = lane >> 4;
  if (mode == 0) {
    #pragma unroll
    for (int mi = 0; mi < 4; ++mi) {
      #pragma unroll
      for (int r = 0; r < 4; ++r) {
        const int row = r0 + wr * 64 + mi * 16 + kq * 4 + r;
        const float mu = STAT[(size_t)row * 2] * (1.0f / Dc);
        const float va = STAT[(size_t)row * 2 + 1] * (1.0f / Dc) - mu * mu;
        const float inv = rsqrtf(va + GN_EPS);
        #pragma unroll
        for (int nj = 0; nj < 4; ++nj) {
          const int col = c0 + wc * 64 + nj * 16 + rl;
          const size_t idx = (size_t)row * Dc + col;
          const float yv = ((float)Y[idx] - mu) * inv * gw[col] + bw[col];
          Gout[idx] = (__bf16)(fmaxf(acc[mi][nj][r], 0.f) * yv);
        }
      }
    }
  } else {
    #pragma unroll
    for (int mi = 0; mi < 4; ++mi) {
      #pragma unroll
      for (int nj = 0; nj < 4; ++nj) {
        const int col = c0 + wc * 64 + nj * 16 + rl;
        #pragma unroll
        for (int r = 0; r < 4; ++r) {
          const int row = r0 + wr * 64 + mi * 16 + kq * 4 + r;
          Fout[(size_t)row * Dc + col] = acc[mi][nj][r];
        }
      }
    }
  }
}

// ---------------------------------------------------------------------------
extern "C" void kernel_launch(void* const* d_in, const int* in_sizes, int n_in,
                              void* d_out, int out_size, void* d_ws, size_t ws_size,
                              hipStream_t stream) {
  const float* x  = (const float*)d_in[0];
  const float* k  = (const float*)d_in[1];
  const float* v  = (const float*)d_in[2];
  const float* Wh = (const float*)d_in[3];
  const float* wg = (const float*)d_in[4];
  const float* wo = (const float*)d_in[5];
  const float* gg = (const float*)d_in[6];
  const float* gb = (const float*)d_in[7];
  float* ws = (float*)d_ws;
  __bf16* Q   = (__bf16*)(ws + OFF_Q);
  __bf16* Kp  = (__bf16*)(ws + OFF_K);
  __bf16* Vt  = (__bf16*)(ws + OFF_VT);
  __bf16* A   = (__bf16*)(ws + OFF_A);
  __bf16* O   = (__bf16*)(ws + OFF_O);
  float*  CT  = ws + OFF_CT;
  float*  PN  = ws + OFF_PN;
  __bf16* XB  = (__bf16*)(ws + OFF_XB);
  __bf16* WGT = (__bf16*)(ws + OFF_WGT);
  __bf16* WOT = (__bf16*)(ws + OFF_WOT);
  float*  TP  = ws + OFF_T;
  __bf16* WHT = (__bf16*)(ws + OFF_WHT);
  float*  STAT= ws + OFF_STAT;
  __bf16* G   = (__bf16*)(ws + OFF_Q);    // reuse Q region (dead after k_ssm)

  // one-time opt-in for dynamic LDS (host-side, graph-capture safe)
  static bool attr_done = false;
  if (!attr_done) {
    (void)hipFuncSetAttribute((const void*)k_mgemm,
                              hipFuncAttributeMaxDynamicSharedMemorySize,
                              MG_LDS);
    (void)hipFuncSetAttribute((const void*)k_projm,
                              hipFuncAttributeMaxDynamicSharedMemorySize,
                              PJ_LDS);
    (void)hipFuncSetAttribute((const void*)k_ssm,
                              hipFuncAttributeMaxDynamicSharedMemorySize,
                              MG_LDS);
    (void)hipFuncSetAttribute((const void*)k_avm,
                              hipFuncAttributeMaxDynamicSharedMemorySize,
                              MG_LDS);
    attr_done = true;
  }

  k_cast8t<<<(BSc * Dc) / (256 * 8), 256, 0, stream>>>(x, XB, CT, PN, TP,
                                                       STAT);
  k_castT2<<<dim3(Dc / 32, Dc / 32, 2), 256, 0, stream>>>(wg, wo, WGT, WOT);
  k_whT<<<dim3(4, 4, Hc), 256, 0, stream>>>(Wh, WHT);
  k_projm<<<dim3(BSc / 128, Hc, 3), 256, PJ_LDS, stream>>>(XB, k, v, WHT,
                                                           Q, Kp, Vt, TP);
  k_ssm<<<dim3(8, 9, Hc), 256, MG_LDS, stream>>>(Q, Kp, CT, PN, A);
  k_avm<<<dim3(8, 1, Bc * Hc), 256, MG_LDS, stream>>>(A, Vt, TP, O, STAT);
  k_mgemm<<<dim3(16, 32), 256, MG_LDS, stream>>>(XB, WGT, O, gg, gb, STAT, G,
                                                 nullptr, 0);
  k_mgemm<<<dim3(16, 32), 256, MG_LDS, stream>>>(G, WOT, nullptr, nullptr,
                                                 nullptr, nullptr, nullptr,
                                                 (float*)d_out, 1);
}